// Round 1
// baseline (1153.573 us; speedup 1.0000x reference)
//
#include <hip/hip_runtime.h>
#include <cstdint>
#include <cstddef>

typedef __bf16 bf16x8_t __attribute__((ext_vector_type(8)));
typedef float f32x4 __attribute__((ext_vector_type(4)));

#define HID 3072
#define NHEADS 24
#define HD 128
#define MLP 12288
#define SEQ 1280
#define IMG 1024
#define N1 21504   /* 3*HID + MLP */
#define QKVW 9216  /* 3*HID */
#define A2W 15360  /* HID + MLP */
#define EPSV 1e-6f

// ---------------- small kernels ----------------
__global__ void silu_kernel(const float* __restrict__ v, float* __restrict__ sv) {
    int i = blockIdx.x * 256 + threadIdx.x;
    float x = v[i];
    sv[i] = x / (1.f + expf(-x));
}

// partial[ky*9216 + n] = sum_{k in [ky*384, +384)} sv[k] * W[k*9216 + n]
__global__ void gemv_part(const float* __restrict__ sv, const float* __restrict__ W,
                          float* __restrict__ part) {
    int n = blockIdx.x * 256 + threadIdx.x;
    int k0 = blockIdx.y * 384;
    float s = 0.f;
    for (int k = k0; k < k0 + 384; ++k)
        s = fmaf(sv[k], W[(size_t)k * QKVW + n], s);
    part[(size_t)blockIdx.y * QKVW + n] = s;
}

__global__ void gemv_reduce(const float* __restrict__ part, const float* __restrict__ bias,
                            float* __restrict__ mod) {
    int n = blockIdx.x * 256 + threadIdx.x;
    float s = bias[n];
    #pragma unroll
    for (int ky = 0; ky < 8; ++ky) s += part[(size_t)ky * QKVW + n];
    mod[n] = s;
}

// LayerNorm + modulate -> bf16 x_mod
__global__ __launch_bounds__(256) void ln_mod_kernel(const float* __restrict__ x,
                                                     const float* __restrict__ mod,
                                                     __bf16* __restrict__ xmod) {
    int m = blockIdx.x;
    int t = threadIdx.x;
    int lane = t & 63, w = t >> 6;
    const float* xr = x + (size_t)m * HID;
    float4 v[3];
    float s = 0.f, sq = 0.f;
    #pragma unroll
    for (int i = 0; i < 3; ++i) {
        v[i] = *reinterpret_cast<const float4*>(&xr[(t + i * 256) * 4]);
        s += v[i].x + v[i].y + v[i].z + v[i].w;
        sq += v[i].x * v[i].x + v[i].y * v[i].y + v[i].z * v[i].z + v[i].w * v[i].w;
    }
    #pragma unroll
    for (int off = 1; off < 64; off <<= 1) {
        s += __shfl_xor(s, off);
        sq += __shfl_xor(sq, off);
    }
    __shared__ float red[8];
    if (lane == 0) { red[w * 2] = s; red[w * 2 + 1] = sq; }
    __syncthreads();
    s = red[0] + red[2] + red[4] + red[6];
    sq = red[1] + red[3] + red[5] + red[7];
    float mu = s * (1.f / HID);
    float var = sq * (1.f / HID) - mu * mu;
    float rs = rsqrtf(var + EPSV);
    #pragma unroll
    for (int i = 0; i < 3; ++i) {
        int n = (t + i * 256) * 4;
        float vals[4] = {v[i].x, v[i].y, v[i].z, v[i].w};
        union { ushort u[4]; uint2 p; } pk;
        #pragma unroll
        for (int c = 0; c < 4; ++c) {
            float xm = (vals[c] - mu) * rs;
            float y = xm * (1.f + mod[HID + n + c]) + mod[n + c];
            __bf16 b = (__bf16)y;
            pk.u[c] = __builtin_bit_cast(ushort, b);
        }
        *reinterpret_cast<uint2*>(&xmod[(size_t)m * HID + n]) = pk.p;
    }
}

// ---------------- GEMM: C = A(bf16) @ B(f32->bf16) + bias, fused epilogues ----------------
// EPI==1: n<9216 -> outf (h_qkv f32, ld 9216); n>=9216 -> gelu -> outb (a2 bf16 at col 3072+(n-9216))
// EPI==3: outf = xres + (acc+bias)*gate   (ld 3072)
template <int EPI>
__global__ __launch_bounds__(256) void gemm_kernel(
    const __bf16* __restrict__ A, const float* __restrict__ B,
    const float* __restrict__ bias, float* __restrict__ outf, __bf16* __restrict__ outb,
    const float* __restrict__ xres, const float* __restrict__ gate,
    int K, int N, int MB) {
    int bid = blockIdx.x;
    int m0 = (bid % MB) * 128;
    int n0 = (bid / MB) * 128;
    __shared__ alignas(16) __bf16 Al[128][40];
    __shared__ alignas(16) __bf16 Bl[128][40];
    int tid = threadIdx.x;
    int lane = tid & 63, wid = tid >> 6;
    int wm = wid >> 1, wn = wid & 1;
    int lr = lane & 15, lg = lane >> 4;
    int bn = tid & 127;   // B stage: n within tile
    int bkh = tid >> 7;   // B stage: k half

    f32x4 acc[4][4] = {};

    for (int kt = 0; kt < K; kt += 32) {
        // stage A (bf16, vector copy)
        #pragma unroll
        for (int cc = 0; cc < 2; ++cc) {
            int c = tid + cc * 256;
            int row = c >> 2, koff = (c & 3) * 8;
            bf16x8_t av = *reinterpret_cast<const bf16x8_t*>(&A[(size_t)(m0 + row) * K + kt + koff]);
            *reinterpret_cast<bf16x8_t*>(&Al[row][koff]) = av;
        }
        // stage B transposed with f32->bf16 conversion
        bf16x8_t bv0, bv1;
        #pragma unroll
        for (int i = 0; i < 16; ++i) {
            float f = B[(size_t)(kt + bkh * 16 + i) * N + n0 + bn];
            if (i < 8) bv0[i] = (__bf16)f; else bv1[i - 8] = (__bf16)f;
        }
        *reinterpret_cast<bf16x8_t*>(&Bl[bn][bkh * 16]) = bv0;
        *reinterpret_cast<bf16x8_t*>(&Bl[bn][bkh * 16 + 8]) = bv1;
        __syncthreads();

        bf16x8_t af[4], bf[4];
        #pragma unroll
        for (int mi = 0; mi < 4; ++mi)
            af[mi] = *reinterpret_cast<const bf16x8_t*>(&Al[wm * 64 + mi * 16 + lr][lg * 8]);
        #pragma unroll
        for (int ni = 0; ni < 4; ++ni)
            bf[ni] = *reinterpret_cast<const bf16x8_t*>(&Bl[wn * 64 + ni * 16 + lr][lg * 8]);
        #pragma unroll
        for (int mi = 0; mi < 4; ++mi)
            #pragma unroll
            for (int ni = 0; ni < 4; ++ni)
                acc[mi][ni] = __builtin_amdgcn_mfma_f32_16x16x32_bf16(af[mi], bf[ni], acc[mi][ni], 0, 0, 0);
        __syncthreads();
    }

    #pragma unroll
    for (int mi = 0; mi < 4; ++mi) {
        #pragma unroll
        for (int ni = 0; ni < 4; ++ni) {
            int col = n0 + wn * 64 + ni * 16 + lr;
            #pragma unroll
            for (int r = 0; r < 4; ++r) {
                int row = m0 + wm * 64 + mi * 16 + lg * 4 + r;
                float val = acc[mi][ni][r] + bias[col];
                if (EPI == 1) {
                    if (n0 < QKVW) {
                        outf[(size_t)row * QKVW + col] = val;
                    } else {
                        float g = 0.5f * val * (1.f + tanhf(0.7978845608028654f * (val + 0.044715f * val * val * val)));
                        outb[(size_t)row * A2W + HID + (col - QKVW)] = (__bf16)g;
                    }
                } else {
                    outf[(size_t)row * HID + col] = xres[(size_t)row * HID + col] + val * gate[col];
                }
            }
        }
    }
}

// ---------------- qkv post: RMSNorm(q,k) + RoPE(img rows) -> (h,l,d) bf16 ----------------
__global__ __launch_bounds__(256) void qkv_post(const float* __restrict__ h,
                                                const float* __restrict__ fc,
                                                const float* __restrict__ fs,
                                                const float* __restrict__ qn,
                                                const float* __restrict__ kn,
                                                __bf16* __restrict__ qb,
                                                __bf16* __restrict__ kb,
                                                __bf16* __restrict__ vb) {
    int m = blockIdx.x;
    int lane = threadIdx.x & 63, w = threadIdx.x >> 6;
    for (int rr = w; rr < 72; rr += 4) {
        int s = rr / 24, hd = rr % 24;
        const float* src = h + (size_t)m * QKVW + s * HID + hd * HD;
        float2 xv = *reinterpret_cast<const float2*>(&src[2 * lane]);
        float x0 = xv.x, x1 = xv.y;
        if (s < 2) {
            float ss = x0 * x0 + x1 * x1;
            #pragma unroll
            for (int off = 1; off < 64; off <<= 1) ss += __shfl_xor(ss, off);
            float rs = rsqrtf(ss * (1.f / HD) + EPSV);
            const float* nw = (s == 0) ? qn : kn;
            x0 *= rs * nw[2 * lane];
            x1 *= rs * nw[2 * lane + 1];
            if (m < IMG) {
                float c0 = fc[m * HD + 2 * lane], c1 = fc[m * HD + 2 * lane + 1];
                float s0 = fs[m * HD + 2 * lane], s1 = fs[m * HD + 2 * lane + 1];
                float r0 = x0 * c0 - x1 * s0;
                float r1 = x1 * c1 + x0 * s1;
                x0 = r0; x1 = r1;
            }
        }
        __bf16* dst = ((s == 0) ? qb : (s == 1) ? kb : vb) + (size_t)hd * SEQ * HD + (size_t)m * HD + 2 * lane;
        ushort u0 = __builtin_bit_cast(ushort, (__bf16)x0);
        ushort u1 = __builtin_bit_cast(ushort, (__bf16)x1);
        *reinterpret_cast<uint*>(dst) = (uint)u0 | ((uint)u1 << 16);
    }
}

// ---------------- flash attention ----------------
// block = 4 waves; wave handles 16 q rows; kv tiles of 32; full (non-causal) attention
__global__ __launch_bounds__(256) void attn_kernel(const __bf16* __restrict__ qb,
                                                   const __bf16* __restrict__ kb,
                                                   const __bf16* __restrict__ vb,
                                                   __bf16* __restrict__ a2) {
    int head = blockIdx.y;
    int tid = threadIdx.x;
    int lane = tid & 63, w = tid >> 6;
    int lr = lane & 15, lg = lane >> 4;
    int q0 = blockIdx.x * 64 + w * 16;
    const __bf16* Q = qb + (size_t)head * SEQ * HD;
    const __bf16* Kp = kb + (size_t)head * SEQ * HD;
    const __bf16* Vp = vb + (size_t)head * SEQ * HD;

    bf16x8_t qf[4];
    #pragma unroll
    for (int kc = 0; kc < 4; ++kc)
        qf[kc] = *reinterpret_cast<const bf16x8_t*>(&Q[(size_t)(q0 + lr) * HD + kc * 32 + lg * 8]);

    __shared__ alignas(16) __bf16 Kl[32][136];
    __shared__ alignas(16) __bf16 Vl[32][136];
    __shared__ float Pl[4][32][16];

    float m_run = -1e30f, l_run = 0.f;
    f32x4 of[8] = {};
    const float sm_scale = 0.08838834764831845f; // 1/sqrt(128)

    for (int kv0 = 0; kv0 < SEQ; kv0 += 32) {
        #pragma unroll
        for (int cc = 0; cc < 2; ++cc) {
            int c = tid + cc * 256;
            int row = c >> 4, off = (c & 15) * 8;
            *reinterpret_cast<bf16x8_t*>(&Kl[row][off]) =
                *reinterpret_cast<const bf16x8_t*>(&Kp[(size_t)(kv0 + row) * HD + off]);
            *reinterpret_cast<bf16x8_t*>(&Vl[row][off]) =
                *reinterpret_cast<const bf16x8_t*>(&Vp[(size_t)(kv0 + row) * HD + off]);
        }
        __syncthreads();

        // S^T = K @ Q^T : lane holds S^T[kv=lg*4+r (+16h)][q=lr]
        f32x4 st[2] = {};
        #pragma unroll
        for (int h = 0; h < 2; ++h)
            #pragma unroll
            for (int kc = 0; kc < 4; ++kc) {
                bf16x8_t kf = *reinterpret_cast<const bf16x8_t*>(&Kl[h * 16 + lr][kc * 32 + lg * 8]);
                st[h] = __builtin_amdgcn_mfma_f32_16x16x32_bf16(kf, qf[kc], st[h], 0, 0, 0);
            }
        float sarr[8];
        #pragma unroll
        for (int h = 0; h < 2; ++h)
            #pragma unroll
            for (int r = 0; r < 4; ++r) sarr[h * 4 + r] = st[h][r] * sm_scale;

        float mloc = sarr[0];
        #pragma unroll
        for (int i = 1; i < 8; ++i) mloc = fmaxf(mloc, sarr[i]);
        mloc = fmaxf(mloc, __shfl_xor(mloc, 16));
        mloc = fmaxf(mloc, __shfl_xor(mloc, 32));
        float m_new = fmaxf(m_run, mloc);
        float alpha = expf(m_run - m_new);
        float p[8], psum = 0.f;
        #pragma unroll
        for (int i = 0; i < 8; ++i) { p[i] = expf(sarr[i] - m_new); psum += p[i]; }
        psum += __shfl_xor(psum, 16);
        psum += __shfl_xor(psum, 32);
        l_run = l_run * alpha + psum;
        m_run = m_new;

        // P^T -> LDS (per-wave region), re-read as A-fragment of P
        #pragma unroll
        for (int h = 0; h < 2; ++h)
            #pragma unroll
            for (int r = 0; r < 4; ++r) Pl[w][h * 16 + lg * 4 + r][lr] = p[h * 4 + r];
        bf16x8_t pa;
        #pragma unroll
        for (int j = 0; j < 8; ++j) pa[j] = (__bf16)Pl[w][lg * 8 + j][lr];

        float alr[4];
        #pragma unroll
        for (int r = 0; r < 4; ++r) alr[r] = __shfl(alpha, lg * 4 + r);

        #pragma unroll
        for (int db = 0; db < 8; ++db) {
            #pragma unroll
            for (int r = 0; r < 4; ++r) of[db][r] *= alr[r];
            bf16x8_t vv;
            #pragma unroll
            for (int j = 0; j < 8; ++j) vv[j] = Vl[lg * 8 + j][db * 16 + lr];
            of[db] = __builtin_amdgcn_mfma_f32_16x16x32_bf16(pa, vv, of[db], 0, 0, 0);
        }
        __syncthreads();
    }

    float lr4[4];
    #pragma unroll
    for (int r = 0; r < 4; ++r) lr4[r] = __shfl(l_run, lg * 4 + r);
    #pragma unroll
    for (int db = 0; db < 8; ++db)
        #pragma unroll
        for (int r = 0; r < 4; ++r) {
            int row = q0 + lg * 4 + r;
            int col = head * HD + db * 16 + lr;
            a2[(size_t)row * A2W + col] = (__bf16)(of[db][r] / lr4[r]);
        }
}

// ---------------- launch ----------------
extern "C" void kernel_launch(void* const* d_in, const int* in_sizes, int n_in,
                              void* d_out, int out_size, void* d_ws, size_t ws_size,
                              hipStream_t stream) {
    const float* x = (const float*)d_in[0];
    const float* vec = (const float*)d_in[1];
    const float* fc = (const float*)d_in[2];
    const float* fs = (const float*)d_in[3];
    const float* mod_w = (const float*)d_in[4];
    const float* mod_b = (const float*)d_in[5];
    const float* w1 = (const float*)d_in[6];
    const float* b1 = (const float*)d_in[7];
    const float* w2 = (const float*)d_in[8];
    const float* b2 = (const float*)d_in[9];
    const float* qn = (const float*)d_in[10];
    const float* kn = (const float*)d_in[11];
    float* out = (float*)d_out;

    char* ws = (char*)d_ws;
    size_t off = 0;
    float* sv = (float*)(ws + off); off += 3072 * 4;                  // silu(vec)
    float* mod = (float*)(ws + off); off += 9216 * 4;                 // modulation
    float* part = (float*)(ws + off); off += 8 * 9216 * 4;            // gemv partials
    off = (off + 255) & ~(size_t)255;
    __bf16* xmod = (__bf16*)(ws + off); off += (size_t)SEQ * HID * 2; // LN+mod bf16
    off = (off + 255) & ~(size_t)255;
    float* hqkv = (float*)(ws + off); off += (size_t)SEQ * QKVW * 4;  // qkv pre-norm f32
    off = (off + 255) & ~(size_t)255;
    __bf16* qb = (__bf16*)(ws + off); off += (size_t)NHEADS * SEQ * HD * 2;
    __bf16* kb = (__bf16*)(ws + off); off += (size_t)NHEADS * SEQ * HD * 2;
    __bf16* vb = (__bf16*)(ws + off); off += (size_t)NHEADS * SEQ * HD * 2;
    off = (off + 255) & ~(size_t)255;
    __bf16* a2 = (__bf16*)(ws + off); off += (size_t)SEQ * A2W * 2;   // [attn | gelu(mlp)]

    silu_kernel<<<12, 256, 0, stream>>>(vec, sv);
    gemv_part<<<dim3(36, 8), 256, 0, stream>>>(sv, mod_w, part);
    gemv_reduce<<<36, 256, 0, stream>>>(part, mod_b, mod);
    ln_mod_kernel<<<SEQ, 256, 0, stream>>>(x, mod, xmod);
    gemm_kernel<1><<<10 * (N1 / 128), 256, 0, stream>>>(xmod, w1, b1, hqkv, a2, nullptr, nullptr,
                                                        HID, N1, 10);
    qkv_post<<<SEQ, 256, 0, stream>>>(hqkv, fc, fs, qn, kn, qb, kb, vb);
    attn_kernel<<<dim3(SEQ / 64, NHEADS), 256, 0, stream>>>(qb, kb, vb, a2);
    gemm_kernel<3><<<10 * (HID / 128), 256, 0, stream>>>(a2, w2, b2, out, nullptr, x, mod + 2 * HID,
                                                         A2W, HID, 10);
}

// Round 2
// 942.846 us; speedup vs baseline: 1.2235x; 1.2235x over previous
//
#include <hip/hip_runtime.h>
#include <cstdint>
#include <cstddef>

typedef __bf16 bf16x8_t __attribute__((ext_vector_type(8)));
typedef float f32x4 __attribute__((ext_vector_type(4)));

#define HID 3072
#define NHEADS 24
#define HD 128
#define MLP 12288
#define SEQ 1280
#define IMG 1024
#define N1 21504   /* 3*HID + MLP */
#define QKVW 9216  /* 3*HID */
#define A2W 15360  /* HID + MLP */
#define EPSV 1e-6f

// ---------------- small kernels ----------------
__global__ void silu_kernel(const float* __restrict__ v, float* __restrict__ sv) {
    int i = blockIdx.x * 256 + threadIdx.x;
    float x = v[i];
    sv[i] = x / (1.f + expf(-x));
}

__global__ void gemv_part(const float* __restrict__ sv, const float* __restrict__ W,
                          float* __restrict__ part) {
    int n = blockIdx.x * 256 + threadIdx.x;
    int k0 = blockIdx.y * 384;
    float s = 0.f;
    for (int k = k0; k < k0 + 384; ++k)
        s = fmaf(sv[k], W[(size_t)k * QKVW + n], s);
    part[(size_t)blockIdx.y * QKVW + n] = s;
}

__global__ void gemv_reduce(const float* __restrict__ part, const float* __restrict__ bias,
                            float* __restrict__ mod) {
    int n = blockIdx.x * 256 + threadIdx.x;
    float s = bias[n];
    #pragma unroll
    for (int ky = 0; ky < 8; ++ky) s += part[(size_t)ky * QKVW + n];
    mod[n] = s;
}

// LayerNorm + modulate -> bf16 x_mod
__global__ __launch_bounds__(256) void ln_mod_kernel(const float* __restrict__ x,
                                                     const float* __restrict__ mod,
                                                     __bf16* __restrict__ xmod) {
    int m = blockIdx.x;
    int t = threadIdx.x;
    int lane = t & 63, w = t >> 6;
    const float* xr = x + (size_t)m * HID;
    float4 v[3];
    float s = 0.f, sq = 0.f;
    #pragma unroll
    for (int i = 0; i < 3; ++i) {
        v[i] = *reinterpret_cast<const float4*>(&xr[(t + i * 256) * 4]);
        s += v[i].x + v[i].y + v[i].z + v[i].w;
        sq += v[i].x * v[i].x + v[i].y * v[i].y + v[i].z * v[i].z + v[i].w * v[i].w;
    }
    #pragma unroll
    for (int off = 1; off < 64; off <<= 1) {
        s += __shfl_xor(s, off);
        sq += __shfl_xor(sq, off);
    }
    __shared__ float red[8];
    if (lane == 0) { red[w * 2] = s; red[w * 2 + 1] = sq; }
    __syncthreads();
    s = red[0] + red[2] + red[4] + red[6];
    sq = red[1] + red[3] + red[5] + red[7];
    float mu = s * (1.f / HID);
    float var = sq * (1.f / HID) - mu * mu;
    float rs = rsqrtf(var + EPSV);
    #pragma unroll
    for (int i = 0; i < 3; ++i) {
        int n = (t + i * 256) * 4;
        float vals[4] = {v[i].x, v[i].y, v[i].z, v[i].w};
        union { ushort u[4]; uint2 p; } pk;
        #pragma unroll
        for (int c = 0; c < 4; ++c) {
            float xm = (vals[c] - mu) * rs;
            float y = xm * (1.f + mod[HID + n + c]) + mod[n + c];
            __bf16 b = (__bf16)y;
            pk.u[c] = __builtin_bit_cast(ushort, b);
        }
        *reinterpret_cast<uint2*>(&xmod[(size_t)m * HID + n]) = pk.p;
    }
}

// ---------------- GEMM: C = A(bf16) @ B(f32->bf16) + bias, fused epilogues ----------------
// Double-buffered LDS, register-staged prefetch, XCD-swizzled grid.
// EPI==1: n<9216 -> outf (h_qkv f32); n>=9216 -> gelu -> outb (a2 bf16 at col 3072+(n-9216))
// EPI==3: outf = xres + (acc+bias)*gate   (ld 3072)
template <int EPI, int BM>
__global__ __launch_bounds__(256) void gemm_kernel(
    const __bf16* __restrict__ A, const float* __restrict__ B,
    const float* __restrict__ bias, float* __restrict__ outf, __bf16* __restrict__ outb,
    const float* __restrict__ xres, const float* __restrict__ gate,
    int K, int N, int MB) {
    constexpr int MI = BM / 32;       // 16x16 m-frags per wave
    constexpr int ACH = BM * 2 / 128; // A 16B-chunks per thread
    // XCD-aware bijective swizzle: all m-tiles of an n-panel land on one XCD
    int xcd = blockIdx.x & 7;
    int t6 = blockIdx.x >> 3;
    int m0 = (t6 % MB) * BM;
    int n0 = (xcd + 8 * (t6 / MB)) * 128;

    __shared__ alignas(16) __bf16 Al[2][BM][40];
    __shared__ alignas(16) __bf16 Bl[2][128][40];

    int tid = threadIdx.x;
    int lane = tid & 63, wid = tid >> 6;
    int wm = wid >> 1, wn = wid & 1;
    int lr = lane & 15, lg = lane >> 4;
    int bn = tid & 127;   // B stage: n within tile
    int bkh = tid >> 7;   // B stage: k half
    const float* Bcol = B + n0 + bn;

    f32x4 acc[MI][4] = {};
    bf16x8_t areg[ACH];
    float breg[16];

    auto loadAB = [&](int kt) {
        #pragma unroll
        for (int i = 0; i < ACH; ++i) {
            int c = tid * ACH + i;
            int row = c >> 2, ko = (c & 3) * 8;
            areg[i] = *reinterpret_cast<const bf16x8_t*>(&A[(size_t)(m0 + row) * K + kt + ko]);
        }
        #pragma unroll
        for (int i = 0; i < 16; ++i)
            breg[i] = Bcol[(size_t)(kt + bkh * 16 + i) * N];
    };
    auto writeAB = [&](int buf) {
        #pragma unroll
        for (int i = 0; i < ACH; ++i) {
            int c = tid * ACH + i;
            int row = c >> 2, ko = (c & 3) * 8;
            *reinterpret_cast<bf16x8_t*>(&Al[buf][row][ko]) = areg[i];
        }
        bf16x8_t bv0, bv1;
        #pragma unroll
        for (int i = 0; i < 8; ++i) {
            bv0[i] = (__bf16)breg[i];
            bv1[i] = (__bf16)breg[i + 8];
        }
        *reinterpret_cast<bf16x8_t*>(&Bl[buf][bn][bkh * 16]) = bv0;
        *reinterpret_cast<bf16x8_t*>(&Bl[buf][bn][bkh * 16 + 8]) = bv1;
    };

    int NT = K / 32;
    loadAB(0);
    writeAB(0);
    __syncthreads();

    for (int t = 0; t < NT; ++t) {
        int cur = t & 1;
        if (t + 1 < NT) loadAB((t + 1) * 32);   // issue next-tile global loads early
        bf16x8_t af[MI], bfr[4];
        #pragma unroll
        for (int mi = 0; mi < MI; ++mi)
            af[mi] = *reinterpret_cast<const bf16x8_t*>(&Al[cur][wm * (MI * 16) + mi * 16 + lr][lg * 8]);
        #pragma unroll
        for (int ni = 0; ni < 4; ++ni)
            bfr[ni] = *reinterpret_cast<const bf16x8_t*>(&Bl[cur][wn * 64 + ni * 16 + lr][lg * 8]);
        #pragma unroll
        for (int mi = 0; mi < MI; ++mi)
            #pragma unroll
            for (int ni = 0; ni < 4; ++ni)
                acc[mi][ni] = __builtin_amdgcn_mfma_f32_16x16x32_bf16(af[mi], bfr[ni], acc[mi][ni], 0, 0, 0);
        if (t + 1 < NT) writeAB(cur ^ 1);       // convert + LDS write after MFMA
        __syncthreads();
    }

    #pragma unroll
    for (int mi = 0; mi < MI; ++mi) {
        #pragma unroll
        for (int ni = 0; ni < 4; ++ni) {
            int col = n0 + wn * 64 + ni * 16 + lr;
            #pragma unroll
            for (int r = 0; r < 4; ++r) {
                int row = m0 + wm * (MI * 16) + mi * 16 + lg * 4 + r;
                float val = acc[mi][ni][r] + bias[col];
                if (EPI == 1) {
                    if (n0 < QKVW) {
                        outf[(size_t)row * QKVW + col] = val;
                    } else {
                        float u = 0.7978845608028654f * (val + 0.044715f * val * val * val);
                        float g = val / (1.f + __expf(-2.f * u));
                        outb[(size_t)row * A2W + HID + (col - QKVW)] = (__bf16)g;
                    }
                } else {
                    outf[(size_t)row * HID + col] = xres[(size_t)row * HID + col] + val * gate[col];
                }
            }
        }
    }
}

// ---------------- qkv post: RMSNorm(q,k) + RoPE(img rows) -> (h,l,d) bf16 ----------------
__global__ __launch_bounds__(256) void qkv_post(const float* __restrict__ h,
                                                const float* __restrict__ fc,
                                                const float* __restrict__ fs,
                                                const float* __restrict__ qn,
                                                const float* __restrict__ kn,
                                                __bf16* __restrict__ qb,
                                                __bf16* __restrict__ kb,
                                                __bf16* __restrict__ vb) {
    int m = blockIdx.x;
    int lane = threadIdx.x & 63, w = threadIdx.x >> 6;
    for (int rr = w; rr < 72; rr += 4) {
        int s = rr / 24, hd = rr % 24;
        const float* src = h + (size_t)m * QKVW + s * HID + hd * HD;
        float2 xv = *reinterpret_cast<const float2*>(&src[2 * lane]);
        float x0 = xv.x, x1 = xv.y;
        if (s < 2) {
            float ss = x0 * x0 + x1 * x1;
            #pragma unroll
            for (int off = 1; off < 64; off <<= 1) ss += __shfl_xor(ss, off);
            float rs = rsqrtf(ss * (1.f / HD) + EPSV);
            const float* nw = (s == 0) ? qn : kn;
            x0 *= rs * nw[2 * lane];
            x1 *= rs * nw[2 * lane + 1];
            if (m < IMG) {
                float c0 = fc[m * HD + 2 * lane], c1 = fc[m * HD + 2 * lane + 1];
                float s0 = fs[m * HD + 2 * lane], s1 = fs[m * HD + 2 * lane + 1];
                float r0 = x0 * c0 - x1 * s0;
                float r1 = x1 * c1 + x0 * s1;
                x0 = r0; x1 = r1;
            }
        }
        __bf16* dst = ((s == 0) ? qb : (s == 1) ? kb : vb) + (size_t)hd * SEQ * HD + (size_t)m * HD + 2 * lane;
        ushort u0 = __builtin_bit_cast(ushort, (__bf16)x0);
        ushort u1 = __builtin_bit_cast(ushort, (__bf16)x1);
        *reinterpret_cast<uint*>(dst) = (uint)u0 | ((uint)u1 << 16);
    }
}

// ---------------- flash attention ----------------
__global__ __launch_bounds__(256) void attn_kernel(const __bf16* __restrict__ qb,
                                                   const __bf16* __restrict__ kb,
                                                   const __bf16* __restrict__ vb,
                                                   __bf16* __restrict__ a2) {
    int head = blockIdx.y;
    int tid = threadIdx.x;
    int lane = tid & 63, w = tid >> 6;
    int lr = lane & 15, lg = lane >> 4;
    int q0 = blockIdx.x * 64 + w * 16;
    const __bf16* Q = qb + (size_t)head * SEQ * HD;
    const __bf16* Kp = kb + (size_t)head * SEQ * HD;
    const __bf16* Vp = vb + (size_t)head * SEQ * HD;

    bf16x8_t qf[4];
    #pragma unroll
    for (int kc = 0; kc < 4; ++kc)
        qf[kc] = *reinterpret_cast<const bf16x8_t*>(&Q[(size_t)(q0 + lr) * HD + kc * 32 + lg * 8]);

    __shared__ alignas(16) __bf16 Kl[32][136];
    __shared__ alignas(16) __bf16 Vl[32][136];
    __shared__ float Pl[4][32][16];

    float m_run = -1e30f, l_run = 0.f;
    f32x4 of[8] = {};
    const float sm_scale = 0.08838834764831845f; // 1/sqrt(128)

    for (int kv0 = 0; kv0 < SEQ; kv0 += 32) {
        #pragma unroll
        for (int cc = 0; cc < 2; ++cc) {
            int c = tid + cc * 256;
            int row = c >> 4, off = (c & 15) * 8;
            *reinterpret_cast<bf16x8_t*>(&Kl[row][off]) =
                *reinterpret_cast<const bf16x8_t*>(&Kp[(size_t)(kv0 + row) * HD + off]);
            *reinterpret_cast<bf16x8_t*>(&Vl[row][off]) =
                *reinterpret_cast<const bf16x8_t*>(&Vp[(size_t)(kv0 + row) * HD + off]);
        }
        __syncthreads();

        f32x4 st[2] = {};
        #pragma unroll
        for (int h = 0; h < 2; ++h)
            #pragma unroll
            for (int kc = 0; kc < 4; ++kc) {
                bf16x8_t kf = *reinterpret_cast<const bf16x8_t*>(&Kl[h * 16 + lr][kc * 32 + lg * 8]);
                st[h] = __builtin_amdgcn_mfma_f32_16x16x32_bf16(kf, qf[kc], st[h], 0, 0, 0);
            }
        float sarr[8];
        #pragma unroll
        for (int h = 0; h < 2; ++h)
            #pragma unroll
            for (int r = 0; r < 4; ++r) sarr[h * 4 + r] = st[h][r] * sm_scale;

        float mloc = sarr[0];
        #pragma unroll
        for (int i = 1; i < 8; ++i) mloc = fmaxf(mloc, sarr[i]);
        mloc = fmaxf(mloc, __shfl_xor(mloc, 16));
        mloc = fmaxf(mloc, __shfl_xor(mloc, 32));
        float m_new = fmaxf(m_run, mloc);
        float alpha = expf(m_run - m_new);
        float p[8], psum = 0.f;
        #pragma unroll
        for (int i = 0; i < 8; ++i) { p[i] = expf(sarr[i] - m_new); psum += p[i]; }
        psum += __shfl_xor(psum, 16);
        psum += __shfl_xor(psum, 32);
        l_run = l_run * alpha + psum;
        m_run = m_new;

        #pragma unroll
        for (int h = 0; h < 2; ++h)
            #pragma unroll
            for (int r = 0; r < 4; ++r) Pl[w][h * 16 + lg * 4 + r][lr] = p[h * 4 + r];
        bf16x8_t pa;
        #pragma unroll
        for (int j = 0; j < 8; ++j) pa[j] = (__bf16)Pl[w][lg * 8 + j][lr];

        float alr[4];
        #pragma unroll
        for (int r = 0; r < 4; ++r) alr[r] = __shfl(alpha, lg * 4 + r);

        #pragma unroll
        for (int db = 0; db < 8; ++db) {
            #pragma unroll
            for (int r = 0; r < 4; ++r) of[db][r] *= alr[r];
            bf16x8_t vv;
            #pragma unroll
            for (int j = 0; j < 8; ++j) vv[j] = Vl[lg * 8 + j][db * 16 + lr];
            of[db] = __builtin_amdgcn_mfma_f32_16x16x32_bf16(pa, vv, of[db], 0, 0, 0);
        }
        __syncthreads();
    }

    float lr4[4];
    #pragma unroll
    for (int r = 0; r < 4; ++r) lr4[r] = __shfl(l_run, lg * 4 + r);
    #pragma unroll
    for (int db = 0; db < 8; ++db)
        #pragma unroll
        for (int r = 0; r < 4; ++r) {
            int row = q0 + lg * 4 + r;
            int col = head * HD + db * 16 + lr;
            a2[(size_t)row * A2W + col] = (__bf16)(of[db][r] / lr4[r]);
        }
}

// ---------------- launch ----------------
extern "C" void kernel_launch(void* const* d_in, const int* in_sizes, int n_in,
                              void* d_out, int out_size, void* d_ws, size_t ws_size,
                              hipStream_t stream) {
    const float* x = (const float*)d_in[0];
    const float* vec = (const float*)d_in[1];
    const float* fc = (const float*)d_in[2];
    const float* fs = (const float*)d_in[3];
    const float* mod_w = (const float*)d_in[4];
    const float* mod_b = (const float*)d_in[5];
    const float* w1 = (const float*)d_in[6];
    const float* b1 = (const float*)d_in[7];
    const float* w2 = (const float*)d_in[8];
    const float* b2 = (const float*)d_in[9];
    const float* qn = (const float*)d_in[10];
    const float* kn = (const float*)d_in[11];
    float* out = (float*)d_out;

    char* ws = (char*)d_ws;
    size_t off = 0;
    float* sv = (float*)(ws + off); off += 3072 * 4;
    float* mod = (float*)(ws + off); off += 9216 * 4;
    float* part = (float*)(ws + off); off += 8 * 9216 * 4;
    off = (off + 255) & ~(size_t)255;
    __bf16* xmod = (__bf16*)(ws + off); off += (size_t)SEQ * HID * 2;
    off = (off + 255) & ~(size_t)255;
    float* hqkv = (float*)(ws + off); off += (size_t)SEQ * QKVW * 4;
    off = (off + 255) & ~(size_t)255;
    __bf16* qb = (__bf16*)(ws + off); off += (size_t)NHEADS * SEQ * HD * 2;
    __bf16* kb = (__bf16*)(ws + off); off += (size_t)NHEADS * SEQ * HD * 2;
    __bf16* vb = (__bf16*)(ws + off); off += (size_t)NHEADS * SEQ * HD * 2;
    off = (off + 255) & ~(size_t)255;
    __bf16* a2 = (__bf16*)(ws + off); off += (size_t)SEQ * A2W * 2;

    silu_kernel<<<12, 256, 0, stream>>>(vec, sv);
    gemv_part<<<dim3(36, 8), 256, 0, stream>>>(sv, mod_w, part);
    gemv_reduce<<<36, 256, 0, stream>>>(part, mod_b, mod);
    ln_mod_kernel<<<SEQ, 256, 0, stream>>>(x, mod, xmod);
    gemm_kernel<1, 128><<<10 * (N1 / 128), 256, 0, stream>>>(xmod, w1, b1, hqkv, a2, nullptr, nullptr,
                                                             HID, N1, 10);
    qkv_post<<<SEQ, 256, 0, stream>>>(hqkv, fc, fs, qn, kn, qb, kb, vb);
    attn_kernel<<<dim3(SEQ / 64, NHEADS), 256, 0, stream>>>(qb, kb, vb, a2);
    gemm_kernel<3, 64><<<20 * (HID / 128), 256, 0, stream>>>(a2, w2, b2, out, nullptr, x, mod + 2 * HID,
                                                             A2W, HID, 20);
}

// Round 3
// 788.249 us; speedup vs baseline: 1.4635x; 1.1961x over previous
//
#include <hip/hip_runtime.h>
#include <cstdint>
#include <cstddef>

typedef __bf16 bf16x8_t __attribute__((ext_vector_type(8)));
typedef float f32x4 __attribute__((ext_vector_type(4)));

#define HID 3072
#define NHEADS 24
#define HD 128
#define MLP 12288
#define SEQ 1280
#define IMG 1024
#define N1 21504   /* 3*HID + MLP */
#define QKVW 9216  /* 3*HID */
#define A2W 15360  /* HID + MLP */
#define EPSV 1e-6f

// ---------------- small kernels ----------------
__global__ void silu_kernel(const float* __restrict__ v, float* __restrict__ sv) {
    int i = blockIdx.x * 256 + threadIdx.x;
    float x = v[i];
    sv[i] = x / (1.f + expf(-x));
}

__global__ void gemv_part(const float* __restrict__ sv, const float* __restrict__ W,
                          float* __restrict__ part) {
    int n = blockIdx.x * 256 + threadIdx.x;
    int k0 = blockIdx.y * 384;
    float s = 0.f;
    for (int k = k0; k < k0 + 384; ++k)
        s = fmaf(sv[k], W[(size_t)k * QKVW + n], s);
    part[(size_t)blockIdx.y * QKVW + n] = s;
}

__global__ void gemv_reduce(const float* __restrict__ part, const float* __restrict__ bias,
                            float* __restrict__ mod) {
    int n = blockIdx.x * 256 + threadIdx.x;
    float s = bias[n];
    #pragma unroll
    for (int ky = 0; ky < 8; ++ky) s += part[(size_t)ky * QKVW + n];
    mod[n] = s;
}

// LayerNorm + modulate -> bf16 x_mod
__global__ __launch_bounds__(256) void ln_mod_kernel(const float* __restrict__ x,
                                                     const float* __restrict__ mod,
                                                     __bf16* __restrict__ xmod) {
    int m = blockIdx.x;
    int t = threadIdx.x;
    int lane = t & 63, w = t >> 6;
    const float* xr = x + (size_t)m * HID;
    float4 v[3];
    float s = 0.f, sq = 0.f;
    #pragma unroll
    for (int i = 0; i < 3; ++i) {
        v[i] = *reinterpret_cast<const float4*>(&xr[(t + i * 256) * 4]);
        s += v[i].x + v[i].y + v[i].z + v[i].w;
        sq += v[i].x * v[i].x + v[i].y * v[i].y + v[i].z * v[i].z + v[i].w * v[i].w;
    }
    #pragma unroll
    for (int off = 1; off < 64; off <<= 1) {
        s += __shfl_xor(s, off);
        sq += __shfl_xor(sq, off);
    }
    __shared__ float red[8];
    if (lane == 0) { red[w * 2] = s; red[w * 2 + 1] = sq; }
    __syncthreads();
    s = red[0] + red[2] + red[4] + red[6];
    sq = red[1] + red[3] + red[5] + red[7];
    float mu = s * (1.f / HID);
    float var = sq * (1.f / HID) - mu * mu;
    float rs = rsqrtf(var + EPSV);
    #pragma unroll
    for (int i = 0; i < 3; ++i) {
        int n = (t + i * 256) * 4;
        float vals[4] = {v[i].x, v[i].y, v[i].z, v[i].w};
        union { ushort u[4]; uint2 p; } pk;
        #pragma unroll
        for (int c = 0; c < 4; ++c) {
            float xm = (vals[c] - mu) * rs;
            float y = xm * (1.f + mod[HID + n + c]) + mod[n + c];
            __bf16 b = (__bf16)y;
            pk.u[c] = __builtin_bit_cast(ushort, b);
        }
        *reinterpret_cast<uint2*>(&xmod[(size_t)m * HID + n]) = pk.p;
    }
}

// LDS swizzle: 32 bf16 (64B) rows, XOR row bits into 16B-slot bits (elem space).
// Keeps 8-elem alignment; spreads 8 consecutive rows' b128 accesses over all 32 banks.
__device__ __forceinline__ int swz(int row, int col) {
    return (row * 32 + col) ^ ((row & 7) << 3);
}

// ---------------- GEMM: C = A(bf16) @ B(f32->bf16), double-buffered, swizzled LDS ----
// EPI==1: n<9216 -> outf (h_qkv f32); n>=9216 -> gelu -> outb (a2 bf16 at col 3072+(n-9216))
// EPI==2: partial write: outf[s*SEQ*HID + row*HID + col] = raw acc (bias in reduce)
template <int EPI, int BM, int SPLITS>
__global__ __launch_bounds__(256) void gemm_kernel(
    const __bf16* __restrict__ A, const float* __restrict__ B,
    const float* __restrict__ bias, float* __restrict__ outf, __bf16* __restrict__ outb,
    int K, int N, int MB) {
    constexpr int MI = BM / 32;       // 16x16 m-frags per wave
    constexpr int ACH = BM / 64;      // A 16B-chunks per thread
    // bijective XCD mapping: all MB m-tiles of a (split,n)-panel land on one XCD
    int bid = blockIdx.x;
    int xcd = bid & 7;
    int v = bid >> 3;
    int ppx = (N / 128) * SPLITS / 8;   // panels per xcd
    int P = xcd * ppx + v / MB;
    int m0 = (v % MB) * BM;
    int s = P / (N / 128);
    int n0 = (P % (N / 128)) * 128;
    int kBeg = s * (K / SPLITS);

    __shared__ alignas(16) __bf16 Al[2][BM * 32];
    __shared__ alignas(16) __bf16 Bl[2][128 * 32];

    int tid = threadIdx.x;
    int lane = tid & 63, wid = tid >> 6;
    int wm = wid >> 1, wn = wid & 1;
    int lr = lane & 15, lg = lane >> 4;
    int bn = tid & 127;   // B stage: n within tile
    int bkh = tid >> 7;   // B stage: k half
    const float* Bcol = B + n0 + bn;

    f32x4 acc[MI][4] = {};
    bf16x8_t areg[ACH];
    float breg[16];

    auto loadAB = [&](int kt) {
        #pragma unroll
        for (int i = 0; i < ACH; ++i) {
            int c = tid * ACH + i;
            int row = c >> 2, ko = (c & 3) * 8;
            areg[i] = *reinterpret_cast<const bf16x8_t*>(&A[(size_t)(m0 + row) * K + kt + ko]);
        }
        #pragma unroll
        for (int i = 0; i < 16; ++i)
            breg[i] = Bcol[(size_t)(kt + bkh * 16 + i) * N];
    };
    auto writeAB = [&](int buf) {
        #pragma unroll
        for (int i = 0; i < ACH; ++i) {
            int c = tid * ACH + i;
            int row = c >> 2, ko = (c & 3) * 8;
            *reinterpret_cast<bf16x8_t*>(&Al[buf][swz(row, ko)]) = areg[i];
        }
        bf16x8_t bv0, bv1;
        #pragma unroll
        for (int i = 0; i < 8; ++i) {
            bv0[i] = (__bf16)breg[i];
            bv1[i] = (__bf16)breg[i + 8];
        }
        *reinterpret_cast<bf16x8_t*>(&Bl[buf][swz(bn, bkh * 16)]) = bv0;
        *reinterpret_cast<bf16x8_t*>(&Bl[buf][swz(bn, bkh * 16 + 8)]) = bv1;
    };

    int NT = K / SPLITS / 32;
    loadAB(kBeg);
    writeAB(0);
    __syncthreads();

    for (int t = 0; t < NT; ++t) {
        int cur = t & 1;
        if (t + 1 < NT) loadAB(kBeg + (t + 1) * 32);
        bf16x8_t af[MI], bfr[4];
        #pragma unroll
        for (int mi = 0; mi < MI; ++mi)
            af[mi] = *reinterpret_cast<const bf16x8_t*>(&Al[cur][swz(wm * (MI * 16) + mi * 16 + lr, lg * 8)]);
        #pragma unroll
        for (int ni = 0; ni < 4; ++ni)
            bfr[ni] = *reinterpret_cast<const bf16x8_t*>(&Bl[cur][swz(wn * 64 + ni * 16 + lr, lg * 8)]);
        #pragma unroll
        for (int mi = 0; mi < MI; ++mi)
            #pragma unroll
            for (int ni = 0; ni < 4; ++ni)
                acc[mi][ni] = __builtin_amdgcn_mfma_f32_16x16x32_bf16(af[mi], bfr[ni], acc[mi][ni], 0, 0, 0);
        if (t + 1 < NT) writeAB(cur ^ 1);
        __syncthreads();
    }

    #pragma unroll
    for (int mi = 0; mi < MI; ++mi) {
        #pragma unroll
        for (int ni = 0; ni < 4; ++ni) {
            int col = n0 + wn * 64 + ni * 16 + lr;
            #pragma unroll
            for (int r = 0; r < 4; ++r) {
                int row = m0 + wm * (MI * 16) + mi * 16 + lg * 4 + r;
                if (EPI == 1) {
                    float val = acc[mi][ni][r] + bias[col];
                    if (n0 < QKVW) {
                        outf[(size_t)row * QKVW + col] = val;
                    } else {
                        float u = 0.7978845608028654f * (val + 0.044715f * val * val * val);
                        float g = val / (1.f + __expf(-2.f * u));
                        outb[(size_t)row * A2W + HID + (col - QKVW)] = (__bf16)g;
                    }
                } else {
                    outf[(size_t)(s * SEQ + row) * HID + col] = acc[mi][ni][r];
                }
            }
        }
    }
}

// out = x + (sum_s part[s] + bias) * gate
__global__ __launch_bounds__(256) void ksplit_reduce(const float* __restrict__ part,
                                                     const float* __restrict__ x,
                                                     const float* __restrict__ bias,
                                                     const float* __restrict__ gate,
                                                     float* __restrict__ out) {
    int i = blockIdx.x * 256 + threadIdx.x;     // quad index over 1280*3072/4
    int col = (i % (HID / 4)) * 4;
    f32x4 a = *reinterpret_cast<const f32x4*>(&part[(size_t)i * 4]);
    #pragma unroll
    for (int s = 1; s < 4; ++s) {
        f32x4 p = *reinterpret_cast<const f32x4*>(&part[(size_t)s * SEQ * HID + (size_t)i * 4]);
        #pragma unroll
        for (int c = 0; c < 4; ++c) a[c] += p[c];
    }
    f32x4 xv = *reinterpret_cast<const f32x4*>(&x[(size_t)i * 4]);
    f32x4 bv = *reinterpret_cast<const f32x4*>(&bias[col]);
    f32x4 gv = *reinterpret_cast<const f32x4*>(&gate[col]);
    f32x4 o;
    #pragma unroll
    for (int c = 0; c < 4; ++c) o[c] = xv[c] + (a[c] + bv[c]) * gv[c];
    *reinterpret_cast<f32x4*>(&out[(size_t)i * 4]) = o;
}

// ---------------- qkv post: RMSNorm(q,k) + RoPE(img rows) -> (h,l,d) bf16 ----------------
__global__ __launch_bounds__(256) void qkv_post(const float* __restrict__ h,
                                                const float* __restrict__ fc,
                                                const float* __restrict__ fs,
                                                const float* __restrict__ qn,
                                                const float* __restrict__ kn,
                                                __bf16* __restrict__ qb,
                                                __bf16* __restrict__ kb,
                                                __bf16* __restrict__ vb) {
    int m = blockIdx.x;
    int lane = threadIdx.x & 63, w = threadIdx.x >> 6;
    for (int rr = w; rr < 72; rr += 4) {
        int s = rr / 24, hd = rr % 24;
        const float* src = h + (size_t)m * QKVW + s * HID + hd * HD;
        float2 xv = *reinterpret_cast<const float2*>(&src[2 * lane]);
        float x0 = xv.x, x1 = xv.y;
        if (s < 2) {
            float ss = x0 * x0 + x1 * x1;
            #pragma unroll
            for (int off = 1; off < 64; off <<= 1) ss += __shfl_xor(ss, off);
            float rs = rsqrtf(ss * (1.f / HD) + EPSV);
            const float* nw = (s == 0) ? qn : kn;
            x0 *= rs * nw[2 * lane];
            x1 *= rs * nw[2 * lane + 1];
            if (m < IMG) {
                float c0 = fc[m * HD + 2 * lane], c1 = fc[m * HD + 2 * lane + 1];
                float s0 = fs[m * HD + 2 * lane], s1 = fs[m * HD + 2 * lane + 1];
                float r0 = x0 * c0 - x1 * s0;
                float r1 = x1 * c1 + x0 * s1;
                x0 = r0; x1 = r1;
            }
        }
        __bf16* dst = ((s == 0) ? qb : (s == 1) ? kb : vb) + (size_t)hd * SEQ * HD + (size_t)m * HD + 2 * lane;
        ushort u0 = __builtin_bit_cast(ushort, (__bf16)x0);
        ushort u1 = __builtin_bit_cast(ushort, (__bf16)x1);
        *reinterpret_cast<uint*>(dst) = (uint)u0 | ((uint)u1 << 16);
    }
}

// ---------------- flash attention ----------------
__global__ __launch_bounds__(256) void attn_kernel(const __bf16* __restrict__ qb,
                                                   const __bf16* __restrict__ kb,
                                                   const __bf16* __restrict__ vb,
                                                   __bf16* __restrict__ a2) {
    int head = blockIdx.y;
    int tid = threadIdx.x;
    int lane = tid & 63, w = tid >> 6;
    int lr = lane & 15, lg = lane >> 4;
    int q0 = blockIdx.x * 64 + w * 16;
    const __bf16* Q = qb + (size_t)head * SEQ * HD;
    const __bf16* Kp = kb + (size_t)head * SEQ * HD;
    const __bf16* Vp = vb + (size_t)head * SEQ * HD;

    bf16x8_t qf[4];
    #pragma unroll
    for (int kc = 0; kc < 4; ++kc)
        qf[kc] = *reinterpret_cast<const bf16x8_t*>(&Q[(size_t)(q0 + lr) * HD + kc * 32 + lg * 8]);

    __shared__ alignas(16) __bf16 Kl[32][136];
    __shared__ alignas(16) __bf16 Vl[32][136];
    __shared__ float Pl[4][32][16];

    float m_run = -1e30f, l_run = 0.f;
    f32x4 of[8] = {};
    const float sm_scale = 0.08838834764831845f; // 1/sqrt(128)

    for (int kv0 = 0; kv0 < SEQ; kv0 += 32) {
        #pragma unroll
        for (int cc = 0; cc < 2; ++cc) {
            int c = tid + cc * 256;
            int row = c >> 4, off = (c & 15) * 8;
            *reinterpret_cast<bf16x8_t*>(&Kl[row][off]) =
                *reinterpret_cast<const bf16x8_t*>(&Kp[(size_t)(kv0 + row) * HD + off]);
            *reinterpret_cast<bf16x8_t*>(&Vl[row][off]) =
                *reinterpret_cast<const bf16x8_t*>(&Vp[(size_t)(kv0 + row) * HD + off]);
        }
        __syncthreads();

        f32x4 st[2] = {};
        #pragma unroll
        for (int h = 0; h < 2; ++h)
            #pragma unroll
            for (int kc = 0; kc < 4; ++kc) {
                bf16x8_t kf = *reinterpret_cast<const bf16x8_t*>(&Kl[h * 16 + lr][kc * 32 + lg * 8]);
                st[h] = __builtin_amdgcn_mfma_f32_16x16x32_bf16(kf, qf[kc], st[h], 0, 0, 0);
            }
        float sarr[8];
        #pragma unroll
        for (int h = 0; h < 2; ++h)
            #pragma unroll
            for (int r = 0; r < 4; ++r) sarr[h * 4 + r] = st[h][r] * sm_scale;

        float mloc = sarr[0];
        #pragma unroll
        for (int i = 1; i < 8; ++i) mloc = fmaxf(mloc, sarr[i]);
        mloc = fmaxf(mloc, __shfl_xor(mloc, 16));
        mloc = fmaxf(mloc, __shfl_xor(mloc, 32));
        float m_new = fmaxf(m_run, mloc);
        float alpha = expf(m_run - m_new);
        float p[8], psum = 0.f;
        #pragma unroll
        for (int i = 0; i < 8; ++i) { p[i] = expf(sarr[i] - m_new); psum += p[i]; }
        psum += __shfl_xor(psum, 16);
        psum += __shfl_xor(psum, 32);
        l_run = l_run * alpha + psum;
        m_run = m_new;

        #pragma unroll
        for (int h = 0; h < 2; ++h)
            #pragma unroll
            for (int r = 0; r < 4; ++r) Pl[w][h * 16 + lg * 4 + r][lr] = p[h * 4 + r];
        bf16x8_t pa;
        #pragma unroll
        for (int j = 0; j < 8; ++j) pa[j] = (__bf16)Pl[w][lg * 8 + j][lr];

        float alr[4];
        #pragma unroll
        for (int r = 0; r < 4; ++r) alr[r] = __shfl(alpha, lg * 4 + r);

        #pragma unroll
        for (int db = 0; db < 8; ++db) {
            #pragma unroll
            for (int r = 0; r < 4; ++r) of[db][r] *= alr[r];
            bf16x8_t vv;
            #pragma unroll
            for (int j = 0; j < 8; ++j) vv[j] = Vl[lg * 8 + j][db * 16 + lr];
            of[db] = __builtin_amdgcn_mfma_f32_16x16x32_bf16(pa, vv, of[db], 0, 0, 0);
        }
        __syncthreads();
    }

    float lr4[4];
    #pragma unroll
    for (int r = 0; r < 4; ++r) lr4[r] = __shfl(l_run, lg * 4 + r);
    #pragma unroll
    for (int db = 0; db < 8; ++db)
        #pragma unroll
        for (int r = 0; r < 4; ++r) {
            int row = q0 + lg * 4 + r;
            int col = head * HD + db * 16 + lr;
            a2[(size_t)row * A2W + col] = (__bf16)(of[db][r] / lr4[r]);
        }
}

// ---------------- launch ----------------
extern "C" void kernel_launch(void* const* d_in, const int* in_sizes, int n_in,
                              void* d_out, int out_size, void* d_ws, size_t ws_size,
                              hipStream_t stream) {
    const float* x = (const float*)d_in[0];
    const float* vec = (const float*)d_in[1];
    const float* fc = (const float*)d_in[2];
    const float* fs = (const float*)d_in[3];
    const float* mod_w = (const float*)d_in[4];
    const float* mod_b = (const float*)d_in[5];
    const float* w1 = (const float*)d_in[6];
    const float* b1 = (const float*)d_in[7];
    const float* w2 = (const float*)d_in[8];
    const float* b2 = (const float*)d_in[9];
    const float* qn = (const float*)d_in[10];
    const float* kn = (const float*)d_in[11];
    float* out = (float*)d_out;

    char* ws = (char*)d_ws;
    size_t off = 0;
    float* sv = (float*)(ws + off); off += 3072 * 4;
    float* mod = (float*)(ws + off); off += 9216 * 4;
    float* part = (float*)(ws + off); off += 8 * 9216 * 4;
    off = (off + 255) & ~(size_t)255;
    __bf16* xmod = (__bf16*)(ws + off); off += (size_t)SEQ * HID * 2;
    off = (off + 255) & ~(size_t)255;
    float* hqkv = (float*)(ws + off); off += (size_t)SEQ * QKVW * 4;
    __bf16* qb = (__bf16*)(ws + off); off += (size_t)NHEADS * SEQ * HD * 2;
    __bf16* kb = (__bf16*)(ws + off); off += (size_t)NHEADS * SEQ * HD * 2;
    __bf16* vb = (__bf16*)(ws + off); off += (size_t)NHEADS * SEQ * HD * 2;
    off = (off + 255) & ~(size_t)255;
    __bf16* a2 = (__bf16*)(ws + off); off += (size_t)SEQ * A2W * 2;
    // k-split partials alias hqkv..vb (dead after attn): 4*1280*3072*4B = 62.9 MB <= 70.8 MB
    float* part2 = hqkv;

    silu_kernel<<<12, 256, 0, stream>>>(vec, sv);
    gemv_part<<<dim3(36, 8), 256, 0, stream>>>(sv, mod_w, part);
    gemv_reduce<<<36, 256, 0, stream>>>(part, mod_b, mod);
    ln_mod_kernel<<<SEQ, 256, 0, stream>>>(x, mod, xmod);
    gemm_kernel<1, 128, 1><<<10 * (N1 / 128), 256, 0, stream>>>(xmod, w1, b1, hqkv, a2, HID, N1, 10);
    qkv_post<<<SEQ, 256, 0, stream>>>(hqkv, fc, fs, qn, kn, qb, kb, vb);
    attn_kernel<<<dim3(SEQ / 64, NHEADS), 256, 0, stream>>>(qb, kb, vb, a2);
    gemm_kernel<2, 64, 4><<<4 * 20 * (HID / 128), 256, 0, stream>>>(a2, w2, nullptr, part2, nullptr,
                                                                    A2W, HID, 20);
    ksplit_reduce<<<SEQ * HID / 1024, 256, 0, stream>>>(part2, x, b2, mod + 2 * HID, out);
}

// Round 4
// 710.206 us; speedup vs baseline: 1.6243x; 1.1099x over previous
//
#include <hip/hip_runtime.h>
#include <cstdint>
#include <cstddef>

typedef __bf16 bf16x8_t __attribute__((ext_vector_type(8)));
typedef float f32x4 __attribute__((ext_vector_type(4)));

#define HID 3072
#define NHEADS 24
#define HD 128
#define MLP 12288
#define SEQ 1280
#define IMG 1024
#define N1 21504   /* 3*HID + MLP */
#define QKVW 9216  /* 3*HID */
#define A2W 15360  /* HID + MLP */
#define EPSV 1e-6f

// async global->LDS, 16B per lane. LDS dest must be wave-uniform base (HW adds lane*16).
__device__ __forceinline__ void gload16(const void* g, void* l) {
    __builtin_amdgcn_global_load_lds(
        (const __attribute__((address_space(1))) unsigned int*)g,
        (__attribute__((address_space(3))) unsigned int*)l, 16, 0, 0);
}

// ---------------- small kernels ----------------
__global__ void silu_kernel(const float* __restrict__ v, float* __restrict__ sv) {
    int i = blockIdx.x * 256 + threadIdx.x;
    float x = v[i];
    sv[i] = x / (1.f + expf(-x));
}

__global__ void gemv_part(const float* __restrict__ sv, const float* __restrict__ W,
                          float* __restrict__ part) {
    int n = blockIdx.x * 256 + threadIdx.x;
    int k0 = blockIdx.y * 384;
    float s = 0.f;
    for (int k = k0; k < k0 + 384; ++k)
        s = fmaf(sv[k], W[(size_t)k * QKVW + n], s);
    part[(size_t)blockIdx.y * QKVW + n] = s;
}

__global__ void gemv_reduce(const float* __restrict__ part, const float* __restrict__ bias,
                            float* __restrict__ mod) {
    int n = blockIdx.x * 256 + threadIdx.x;
    float s = bias[n];
    #pragma unroll
    for (int ky = 0; ky < 8; ++ky) s += part[(size_t)ky * QKVW + n];
    mod[n] = s;
}

// LayerNorm + modulate -> bf16 x_mod
__global__ __launch_bounds__(256) void ln_mod_kernel(const float* __restrict__ x,
                                                     const float* __restrict__ mod,
                                                     __bf16* __restrict__ xmod) {
    int m = blockIdx.x;
    int t = threadIdx.x;
    int lane = t & 63, w = t >> 6;
    const float* xr = x + (size_t)m * HID;
    float4 v[3];
    float s = 0.f, sq = 0.f;
    #pragma unroll
    for (int i = 0; i < 3; ++i) {
        v[i] = *reinterpret_cast<const float4*>(&xr[(t + i * 256) * 4]);
        s += v[i].x + v[i].y + v[i].z + v[i].w;
        sq += v[i].x * v[i].x + v[i].y * v[i].y + v[i].z * v[i].z + v[i].w * v[i].w;
    }
    #pragma unroll
    for (int off = 1; off < 64; off <<= 1) {
        s += __shfl_xor(s, off);
        sq += __shfl_xor(sq, off);
    }
    __shared__ float red[8];
    if (lane == 0) { red[w * 2] = s; red[w * 2 + 1] = sq; }
    __syncthreads();
    s = red[0] + red[2] + red[4] + red[6];
    sq = red[1] + red[3] + red[5] + red[7];
    float mu = s * (1.f / HID);
    float var = sq * (1.f / HID) - mu * mu;
    float rs = rsqrtf(var + EPSV);
    #pragma unroll
    for (int i = 0; i < 3; ++i) {
        int n = (t + i * 256) * 4;
        float vals[4] = {v[i].x, v[i].y, v[i].z, v[i].w};
        union { ushort u[4]; uint2 p; } pk;
        #pragma unroll
        for (int c = 0; c < 4; ++c) {
            float xm = (vals[c] - mu) * rs;
            float y = xm * (1.f + mod[HID + n + c]) + mod[n + c];
            __bf16 b = (__bf16)y;
            pk.u[c] = __builtin_bit_cast(ushort, b);
        }
        *reinterpret_cast<uint2*>(&xmod[(size_t)m * HID + n]) = pk.p;
    }
}

// ---------------- transpose-convert: in [R][C] f32 -> out [C][R] bf16 ----------------
__global__ __launch_bounds__(256) void convT_kernel(const float* __restrict__ in,
                                                    __bf16* __restrict__ out, int R, int C) {
    __shared__ float t[64][65];
    int nbr = R >> 6;
    int tr = blockIdx.x % nbr, tc = blockIdx.x / nbr;
    int r0 = tr * 64, c0 = tc * 64;
    int tid = threadIdx.x;
    int rr = tid >> 2, cg = (tid & 3) * 16;
    #pragma unroll
    for (int j = 0; j < 4; ++j) {
        float4 v = *reinterpret_cast<const float4*>(&in[(size_t)(r0 + rr) * C + c0 + cg + j * 4]);
        t[rr][cg + j * 4 + 0] = v.x;
        t[rr][cg + j * 4 + 1] = v.y;
        t[rr][cg + j * 4 + 2] = v.z;
        t[rr][cg + j * 4 + 3] = v.w;
    }
    __syncthreads();
    int cc = tid >> 2, rg = (tid & 3) * 16;
    union { ushort u[16]; uint4 q[2]; } pk;
    #pragma unroll
    for (int j = 0; j < 16; ++j)
        pk.u[j] = __builtin_bit_cast(ushort, (__bf16)t[rg + j][cc]);
    __bf16* dst = &out[(size_t)(c0 + cc) * R + r0 + rg];
    *reinterpret_cast<uint4*>(dst) = pk.q[0];
    *reinterpret_cast<uint4*>(dst + 8) = pk.q[1];
}

// ---------------- bf16 GEMM, m97-style: global_load_lds staging, 2-phase dbuf ----------
// A: [M][K] bf16 row-major; BT: [N][K] bf16 (n-major, pre-transposed)
// EPI==1: n<9216 -> outf (h_qkv f32); n>=9216 -> gelu -> outb (a2 bf16 at col 3072+(n-9216))
// EPI==2: partial write: outf[s*SEQ*HID + row*HID + col] = raw acc (bias in reduce)
template <int EPI, int SPLITS>
__global__ __launch_bounds__(256) void gemm_bf16(
    const __bf16* __restrict__ A, const __bf16* __restrict__ BT,
    const float* __restrict__ bias, float* __restrict__ outf, __bf16* __restrict__ outb,
    int K, int N, int MB) {
    // bijective XCD mapping: all MB m-tiles of a (split,n)-panel land on one XCD
    int bid = blockIdx.x;
    int xcd = bid & 7;
    int v = bid >> 3;
    int ppx = (N / 128) * SPLITS / 8;
    int P = xcd * ppx + v / MB;
    int m0 = (v % MB) * 128;
    int s = P / (N / 128);
    int n0 = (P % (N / 128)) * 128;
    int kBeg = s * (K / SPLITS);
    int NT = K / SPLITS / 32;

    __shared__ alignas(16) __bf16 Al[2][128 * 32];
    __shared__ alignas(16) __bf16 Bl[2][128 * 32];

    int tid = threadIdx.x;
    int lane = tid & 63, wid = tid >> 6;
    int wm = wid >> 1, wn = wid & 1;
    int lr = lane & 15, lg = lane >> 4;

    // staging: wave w stages tile rows [w*32, w*32+32) with 2 gload16 per operand.
    // lane l covers row w*32+j*16+(l>>2), k-chunk (l&3)*8  (LDS ends up row-major [128][32])
    const __bf16* gA = A + (size_t)(m0 + wid * 32 + (lane >> 2)) * K + (lane & 3) * 8;
    const __bf16* gB = BT + (size_t)(n0 + wid * 32 + (lane >> 2)) * K + (lane & 3) * 8;
    int ldsOff0 = (wid * 32) * 32;       // elems
    int ldsOff1 = (wid * 32 + 16) * 32;

    f32x4 acc[4][4] = {};

    auto stage = [&](int buf, int kt) {
        gload16(gA + kt, &Al[buf][ldsOff0]);
        gload16(gA + (size_t)16 * K + kt, &Al[buf][ldsOff1]);
        gload16(gB + kt, &Bl[buf][ldsOff0]);
        gload16(gB + (size_t)16 * K + kt, &Bl[buf][ldsOff1]);
    };

    stage(0, kBeg);
    __syncthreads();

    for (int t = 0; t < NT; ++t) {
        int cur = t & 1;
        if (t + 1 < NT) stage(cur ^ 1, kBeg + (t + 1) * 32);
        bf16x8_t af[4], bfr[4];
        #pragma unroll
        for (int mi = 0; mi < 4; ++mi)
            af[mi] = *reinterpret_cast<const bf16x8_t*>(&Al[cur][(wm * 64 + mi * 16 + lr) * 32 + lg * 8]);
        #pragma unroll
        for (int ni = 0; ni < 4; ++ni)
            bfr[ni] = *reinterpret_cast<const bf16x8_t*>(&Bl[cur][(wn * 64 + ni * 16 + lr) * 32 + lg * 8]);
        #pragma unroll
        for (int mi = 0; mi < 4; ++mi)
            #pragma unroll
            for (int ni = 0; ni < 4; ++ni)
                acc[mi][ni] = __builtin_amdgcn_mfma_f32_16x16x32_bf16(af[mi], bfr[ni], acc[mi][ni], 0, 0, 0);
        __syncthreads();   // drains vmcnt (compiler) -> buf cur^1 ready
    }

    #pragma unroll
    for (int mi = 0; mi < 4; ++mi) {
        #pragma unroll
        for (int ni = 0; ni < 4; ++ni) {
            int col = n0 + wn * 64 + ni * 16 + lr;
            #pragma unroll
            for (int r = 0; r < 4; ++r) {
                int row = m0 + wm * 64 + mi * 16 + lg * 4 + r;
                if (EPI == 1) {
                    float val = acc[mi][ni][r] + bias[col];
                    if (n0 < QKVW) {
                        outf[(size_t)row * QKVW + col] = val;
                    } else {
                        float u = 0.7978845608028654f * (val + 0.044715f * val * val * val);
                        float g = val / (1.f + __expf(-2.f * u));
                        outb[(size_t)row * A2W + HID + (col - QKVW)] = (__bf16)g;
                    }
                } else {
                    outf[(size_t)(s * SEQ + row) * HID + col] = acc[mi][ni][r];
                }
            }
        }
    }
}

// ---------------- fallback GEMM (R3): f32 B with in-loop convert ----------------
__device__ __forceinline__ int swz(int row, int col) {
    return (row * 32 + col) ^ ((row & 7) << 3);
}

template <int EPI, int BM, int SPLITS>
__global__ __launch_bounds__(256) void gemm_kernel(
    const __bf16* __restrict__ A, const float* __restrict__ B,
    const float* __restrict__ bias, float* __restrict__ outf, __bf16* __restrict__ outb,
    int K, int N, int MB) {
    constexpr int MI = BM / 32;
    constexpr int ACH = BM / 64;
    int bid = blockIdx.x;
    int xcd = bid & 7;
    int v = bid >> 3;
    int ppx = (N / 128) * SPLITS / 8;
    int P = xcd * ppx + v / MB;
    int m0 = (v % MB) * BM;
    int s = P / (N / 128);
    int n0 = (P % (N / 128)) * 128;
    int kBeg = s * (K / SPLITS);

    __shared__ alignas(16) __bf16 Al[2][BM * 32];
    __shared__ alignas(16) __bf16 Bl[2][128 * 32];

    int tid = threadIdx.x;
    int lane = tid & 63, wid = tid >> 6;
    int wm = wid >> 1, wn = wid & 1;
    int lr = lane & 15, lg = lane >> 4;
    int bn = tid & 127;
    int bkh = tid >> 7;
    const float* Bcol = B + n0 + bn;

    f32x4 acc[MI][4] = {};
    bf16x8_t areg[ACH];
    float breg[16];

    auto loadAB = [&](int kt) {
        #pragma unroll
        for (int i = 0; i < ACH; ++i) {
            int c = tid * ACH + i;
            int row = c >> 2, ko = (c & 3) * 8;
            areg[i] = *reinterpret_cast<const bf16x8_t*>(&A[(size_t)(m0 + row) * K + kt + ko]);
        }
        #pragma unroll
        for (int i = 0; i < 16; ++i)
            breg[i] = Bcol[(size_t)(kt + bkh * 16 + i) * N];
    };
    auto writeAB = [&](int buf) {
        #pragma unroll
        for (int i = 0; i < ACH; ++i) {
            int c = tid * ACH + i;
            int row = c >> 2, ko = (c & 3) * 8;
            *reinterpret_cast<bf16x8_t*>(&Al[buf][swz(row, ko)]) = areg[i];
        }
        bf16x8_t bv0, bv1;
        #pragma unroll
        for (int i = 0; i < 8; ++i) {
            bv0[i] = (__bf16)breg[i];
            bv1[i] = (__bf16)breg[i + 8];
        }
        *reinterpret_cast<bf16x8_t*>(&Bl[buf][swz(bn, bkh * 16)]) = bv0;
        *reinterpret_cast<bf16x8_t*>(&Bl[buf][swz(bn, bkh * 16 + 8)]) = bv1;
    };

    int NT = K / SPLITS / 32;
    loadAB(kBeg);
    writeAB(0);
    __syncthreads();

    for (int t = 0; t < NT; ++t) {
        int cur = t & 1;
        if (t + 1 < NT) loadAB(kBeg + (t + 1) * 32);
        bf16x8_t af[MI], bfr[4];
        #pragma unroll
        for (int mi = 0; mi < MI; ++mi)
            af[mi] = *reinterpret_cast<const bf16x8_t*>(&Al[cur][swz(wm * (MI * 16) + mi * 16 + lr, lg * 8)]);
        #pragma unroll
        for (int ni = 0; ni < 4; ++ni)
            bfr[ni] = *reinterpret_cast<const bf16x8_t*>(&Bl[cur][swz(wn * 64 + ni * 16 + lr, lg * 8)]);
        #pragma unroll
        for (int mi = 0; mi < MI; ++mi)
            #pragma unroll
            for (int ni = 0; ni < 4; ++ni)
                acc[mi][ni] = __builtin_amdgcn_mfma_f32_16x16x32_bf16(af[mi], bfr[ni], acc[mi][ni], 0, 0, 0);
        if (t + 1 < NT) writeAB(cur ^ 1);
        __syncthreads();
    }

    #pragma unroll
    for (int mi = 0; mi < MI; ++mi) {
        #pragma unroll
        for (int ni = 0; ni < 4; ++ni) {
            int col = n0 + wn * 64 + ni * 16 + lr;
            #pragma unroll
            for (int r = 0; r < 4; ++r) {
                int row = m0 + wm * (MI * 16) + mi * 16 + lg * 4 + r;
                if (EPI == 1) {
                    float val = acc[mi][ni][r] + bias[col];
                    if (n0 < QKVW) {
                        outf[(size_t)row * QKVW + col] = val;
                    } else {
                        float u = 0.7978845608028654f * (val + 0.044715f * val * val * val);
                        float g = val / (1.f + __expf(-2.f * u));
                        outb[(size_t)row * A2W + HID + (col - QKVW)] = (__bf16)g;
                    }
                } else {
                    outf[(size_t)(s * SEQ + row) * HID + col] = acc[mi][ni][r];
                }
            }
        }
    }
}

// out = x + (sum_s part[s] + bias) * gate
__global__ __launch_bounds__(256) void ksplit_reduce(const float* __restrict__ part,
                                                     const float* __restrict__ x,
                                                     const float* __restrict__ bias,
                                                     const float* __restrict__ gate,
                                                     float* __restrict__ out) {
    int i = blockIdx.x * 256 + threadIdx.x;
    int col = (i % (HID / 4)) * 4;
    f32x4 a = *reinterpret_cast<const f32x4*>(&part[(size_t)i * 4]);
    #pragma unroll
    for (int s = 1; s < 4; ++s) {
        f32x4 p = *reinterpret_cast<const f32x4*>(&part[(size_t)s * SEQ * HID + (size_t)i * 4]);
        #pragma unroll
        for (int c = 0; c < 4; ++c) a[c] += p[c];
    }
    f32x4 xv = *reinterpret_cast<const f32x4*>(&x[(size_t)i * 4]);
    f32x4 bv = *reinterpret_cast<const f32x4*>(&bias[col]);
    f32x4 gv = *reinterpret_cast<const f32x4*>(&gate[col]);
    f32x4 o;
    #pragma unroll
    for (int c = 0; c < 4; ++c) o[c] = xv[c] + (a[c] + bv[c]) * gv[c];
    *reinterpret_cast<f32x4*>(&out[(size_t)i * 4]) = o;
}

// ---------------- qkv post: RMSNorm(q,k) + RoPE(img rows) -> (h,l,d) bf16 ----------------
__global__ __launch_bounds__(256) void qkv_post(const float* __restrict__ h,
                                                const float* __restrict__ fc,
                                                const float* __restrict__ fs,
                                                const float* __restrict__ qn,
                                                const float* __restrict__ kn,
                                                __bf16* __restrict__ qb,
                                                __bf16* __restrict__ kb,
                                                __bf16* __restrict__ vb) {
    int m = blockIdx.x;
    int lane = threadIdx.x & 63, w = threadIdx.x >> 6;
    for (int rr = w; rr < 72; rr += 4) {
        int s = rr / 24, hd = rr % 24;
        const float* src = h + (size_t)m * QKVW + s * HID + hd * HD;
        float2 xv = *reinterpret_cast<const float2*>(&src[2 * lane]);
        float x0 = xv.x, x1 = xv.y;
        if (s < 2) {
            float ss = x0 * x0 + x1 * x1;
            #pragma unroll
            for (int off = 1; off < 64; off <<= 1) ss += __shfl_xor(ss, off);
            float rs = rsqrtf(ss * (1.f / HD) + EPSV);
            const float* nw = (s == 0) ? qn : kn;
            x0 *= rs * nw[2 * lane];
            x1 *= rs * nw[2 * lane + 1];
            if (m < IMG) {
                float c0 = fc[m * HD + 2 * lane], c1 = fc[m * HD + 2 * lane + 1];
                float s0 = fs[m * HD + 2 * lane], s1 = fs[m * HD + 2 * lane + 1];
                float r0 = x0 * c0 - x1 * s0;
                float r1 = x1 * c1 + x0 * s1;
                x0 = r0; x1 = r1;
            }
        }
        __bf16* dst = ((s == 0) ? qb : (s == 1) ? kb : vb) + (size_t)hd * SEQ * HD + (size_t)m * HD + 2 * lane;
        ushort u0 = __builtin_bit_cast(ushort, (__bf16)x0);
        ushort u1 = __builtin_bit_cast(ushort, (__bf16)x1);
        *reinterpret_cast<uint*>(dst) = (uint)u0 | ((uint)u1 << 16);
    }
}

// ---------------- flash attention ----------------
__global__ __launch_bounds__(256) void attn_kernel(const __bf16* __restrict__ qb,
                                                   const __bf16* __restrict__ kb,
                                                   const __bf16* __restrict__ vb,
                                                   __bf16* __restrict__ a2) {
    int head = blockIdx.y;
    int tid = threadIdx.x;
    int lane = tid & 63, w = tid >> 6;
    int lr = lane & 15, lg = lane >> 4;
    int q0 = blockIdx.x * 64 + w * 16;
    const __bf16* Q = qb + (size_t)head * SEQ * HD;
    const __bf16* Kp = kb + (size_t)head * SEQ * HD;
    const __bf16* Vp = vb + (size_t)head * SEQ * HD;

    bf16x8_t qf[4];
    #pragma unroll
    for (int kc = 0; kc < 4; ++kc)
        qf[kc] = *reinterpret_cast<const bf16x8_t*>(&Q[(size_t)(q0 + lr) * HD + kc * 32 + lg * 8]);

    __shared__ alignas(16) __bf16 Kl[32][136];
    __shared__ alignas(16) __bf16 Vl[32][136];
    __shared__ float Pl[4][32][16];

    float m_run = -1e30f, l_run = 0.f;
    f32x4 of[8] = {};
    const float sm_scale = 0.08838834764831845f;

    for (int kv0 = 0; kv0 < SEQ; kv0 += 32) {
        #pragma unroll
        for (int cc = 0; cc < 2; ++cc) {
            int c = tid + cc * 256;
            int row = c >> 4, off = (c & 15) * 8;
            *reinterpret_cast<bf16x8_t*>(&Kl[row][off]) =
                *reinterpret_cast<const bf16x8_t*>(&Kp[(size_t)(kv0 + row) * HD + off]);
            *reinterpret_cast<bf16x8_t*>(&Vl[row][off]) =
                *reinterpret_cast<const bf16x8_t*>(&Vp[(size_t)(kv0 + row) * HD + off]);
        }
        __syncthreads();

        f32x4 st[2] = {};
        #pragma unroll
        for (int h = 0; h < 2; ++h)
            #pragma unroll
            for (int kc = 0; kc < 4; ++kc) {
                bf16x8_t kf = *reinterpret_cast<const bf16x8_t*>(&Kl[h * 16 + lr][kc * 32 + lg * 8]);
                st[h] = __builtin_amdgcn_mfma_f32_16x16x32_bf16(kf, qf[kc], st[h], 0, 0, 0);
            }
        float sarr[8];
        #pragma unroll
        for (int h = 0; h < 2; ++h)
            #pragma unroll
            for (int r = 0; r < 4; ++r) sarr[h * 4 + r] = st[h][r] * sm_scale;

        float mloc = sarr[0];
        #pragma unroll
        for (int i = 1; i < 8; ++i) mloc = fmaxf(mloc, sarr[i]);
        mloc = fmaxf(mloc, __shfl_xor(mloc, 16));
        mloc = fmaxf(mloc, __shfl_xor(mloc, 32));
        float m_new = fmaxf(m_run, mloc);
        float alpha = expf(m_run - m_new);
        float p[8], psum = 0.f;
        #pragma unroll
        for (int i = 0; i < 8; ++i) { p[i] = expf(sarr[i] - m_new); psum += p[i]; }
        psum += __shfl_xor(psum, 16);
        psum += __shfl_xor(psum, 32);
        l_run = l_run * alpha + psum;
        m_run = m_new;

        #pragma unroll
        for (int h = 0; h < 2; ++h)
            #pragma unroll
            for (int r = 0; r < 4; ++r) Pl[w][h * 16 + lg * 4 + r][lr] = p[h * 4 + r];
        bf16x8_t pa;
        #pragma unroll
        for (int j = 0; j < 8; ++j) pa[j] = (__bf16)Pl[w][lg * 8 + j][lr];

        float alr[4];
        #pragma unroll
        for (int r = 0; r < 4; ++r) alr[r] = __shfl(alpha, lg * 4 + r);

        #pragma unroll
        for (int db = 0; db < 8; ++db) {
            #pragma unroll
            for (int r = 0; r < 4; ++r) of[db][r] *= alr[r];
            bf16x8_t vv;
            #pragma unroll
            for (int j = 0; j < 8; ++j) vv[j] = Vl[lg * 8 + j][db * 16 + lr];
            of[db] = __builtin_amdgcn_mfma_f32_16x16x32_bf16(pa, vv, of[db], 0, 0, 0);
        }
        __syncthreads();
    }

    float lr4[4];
    #pragma unroll
    for (int r = 0; r < 4; ++r) lr4[r] = __shfl(l_run, lg * 4 + r);
    #pragma unroll
    for (int db = 0; db < 8; ++db)
        #pragma unroll
        for (int r = 0; r < 4; ++r) {
            int row = q0 + lg * 4 + r;
            int col = head * HD + db * 16 + lr;
            a2[(size_t)row * A2W + col] = (__bf16)(of[db][r] / lr4[r]);
        }
}

// ---------------- launch ----------------
extern "C" void kernel_launch(void* const* d_in, const int* in_sizes, int n_in,
                              void* d_out, int out_size, void* d_ws, size_t ws_size,
                              hipStream_t stream) {
    const float* x = (const float*)d_in[0];
    const float* vec = (const float*)d_in[1];
    const float* fc = (const float*)d_in[2];
    const float* fs = (const float*)d_in[3];
    const float* mod_w = (const float*)d_in[4];
    const float* mod_b = (const float*)d_in[5];
    const float* w1 = (const float*)d_in[6];
    const float* b1 = (const float*)d_in[7];
    const float* w2 = (const float*)d_in[8];
    const float* b2 = (const float*)d_in[9];
    const float* qn = (const float*)d_in[10];
    const float* kn = (const float*)d_in[11];
    float* out = (float*)d_out;

    char* ws = (char*)d_ws;
    size_t off = 0;
    float* sv = (float*)(ws + off); off += 3072 * 4;
    float* mod = (float*)(ws + off); off += 9216 * 4;
    float* part = (float*)(ws + off); off += 8 * 9216 * 4;
    off = (off + 255) & ~(size_t)255;
    __bf16* xmod = (__bf16*)(ws + off); off += (size_t)SEQ * HID * 2;
    off = (off + 255) & ~(size_t)255;
    float* hqkv = (float*)(ws + off); off += (size_t)SEQ * QKVW * 4;
    __bf16* qb = (__bf16*)(ws + off); off += (size_t)NHEADS * SEQ * HD * 2;
    __bf16* kb = (__bf16*)(ws + off); off += (size_t)NHEADS * SEQ * HD * 2;
    __bf16* vb = (__bf16*)(ws + off); off += (size_t)NHEADS * SEQ * HD * 2;
    off = (off + 255) & ~(size_t)255;
    __bf16* a2 = (__bf16*)(ws + off); off += (size_t)SEQ * A2W * 2;
    float* part2 = hqkv;   // 4 splits * SEQ*HID f32 = 63MB aliases hqkv+qb+kb (dead by then)

    off = (off + 255) & ~(size_t)255;
    __bf16* w1b = (__bf16*)(ws + off);
    size_t need = off + (size_t)N1 * HID * 2;   // w1b (w2b aliases w1b)
    __bf16* w2b = w1b;

    silu_kernel<<<12, 256, 0, stream>>>(vec, sv);
    gemv_part<<<dim3(36, 8), 256, 0, stream>>>(sv, mod_w, part);
    gemv_reduce<<<36, 256, 0, stream>>>(part, mod_b, mod);
    ln_mod_kernel<<<SEQ, 256, 0, stream>>>(x, mod, xmod);

    if (ws_size >= need) {
        // fast path: pre-transposed bf16 weights + global_load_lds GEMMs
        convT_kernel<<<48 * 336, 256, 0, stream>>>(w1, w1b, HID, N1);        // w1b [N1][HID]
        gemm_bf16<1, 1><<<10 * (N1 / 128), 256, 0, stream>>>(xmod, w1b, b1, hqkv, a2, HID, N1, 10);
        convT_kernel<<<240 * 48, 256, 0, stream>>>(w2, w2b, A2W, HID);       // w2b [HID][A2W]
        qkv_post<<<SEQ, 256, 0, stream>>>(hqkv, fc, fs, qn, kn, qb, kb, vb);
        attn_kernel<<<dim3(SEQ / 64, NHEADS), 256, 0, stream>>>(qb, kb, vb, a2);
        gemm_bf16<2, 4><<<4 * 10 * (HID / 128), 256, 0, stream>>>(a2, w2b, nullptr, part2, nullptr,
                                                                  A2W, HID, 10);
    } else {
        // fallback: in-loop f32->bf16 conversion GEMMs (R3 path)
        gemm_kernel<1, 128, 1><<<10 * (N1 / 128), 256, 0, stream>>>(xmod, w1, b1, hqkv, a2, HID, N1, 10);
        qkv_post<<<SEQ, 256, 0, stream>>>(hqkv, fc, fs, qn, kn, qb, kb, vb);
        attn_kernel<<<dim3(SEQ / 64, NHEADS), 256, 0, stream>>>(qb, kb, vb, a2);
        gemm_kernel<2, 64, 4><<<4 * 20 * (HID / 128), 256, 0, stream>>>(a2, w2, nullptr, part2, nullptr,
                                                                        A2W, HID, 20);
    }
    ksplit_reduce<<<SEQ * HID / 1024, 256, 0, stream>>>(part2, x, b2, mod + 2 * HID, out);
}

// Round 5
// 684.471 us; speedup vs baseline: 1.6853x; 1.0376x over previous
//
#include <hip/hip_runtime.h>
#include <cstdint>
#include <cstddef>

typedef __bf16 bf16x8_t __attribute__((ext_vector_type(8)));
typedef float f32x4 __attribute__((ext_vector_type(4)));

#define HID 3072
#define NHEADS 24
#define HD 128
#define MLP 12288
#define SEQ 1280
#define IMG 1024
#define N1 21504   /* 3*HID + MLP */
#define QKVW 9216  /* 3*HID */
#define A2W 15360  /* HID + MLP */
#define EPSV 1e-6f

// Tiled bf16 operand layout ("fragment-block" order):
// element (row, col) of a [rows][K] operand lives at:
//   tile (row>>8, col>>6) -> 16384-elem image of 32 blocks x 512 elems:
//   block = ((col>>5)&1)*16 + ((row>>4)&15)         (k32 , row16)
//   slot  = (row&15) + ((col>>3)&3)*16              (lane = lr + lg*16)
//   elem  = block*512 + slot*8 + (col&7)
// One block = 1024B = one wave ds_read_b128 / global_load_lds_dwordx4 unit.
__device__ __forceinline__ size_t tpos(int row, int col, int KT) {
    return ((size_t)(row >> 8) * KT + (col >> 6)) * 16384
         + (size_t)(((((col >> 5) & 1) << 4) + ((row >> 4) & 15)) * 512
                    + (((row & 15) + (((col >> 3) & 3) << 4)) << 3) + (col & 7));
}

// async global->LDS, 16B per lane (HW adds lane*16 to wave-uniform LDS base)
__device__ __forceinline__ void gload16(const void* g, void* l) {
    __builtin_amdgcn_global_load_lds(
        (const __attribute__((address_space(1))) unsigned int*)g,
        (__attribute__((address_space(3))) unsigned int*)l, 16, 0, 0);
}

__device__ __forceinline__ void bar() {
    asm volatile("" ::: "memory");
    __builtin_amdgcn_s_barrier();
    asm volatile("" ::: "memory");
}

// ---------------- small kernels ----------------
__global__ void silu_kernel(const float* __restrict__ v, float* __restrict__ sv) {
    int i = blockIdx.x * 256 + threadIdx.x;
    float x = v[i];
    sv[i] = x / (1.f + expf(-x));
}

__global__ void gemv_part(const float* __restrict__ sv, const float* __restrict__ W,
                          float* __restrict__ part) {
    int n = blockIdx.x * 256 + threadIdx.x;
    int k0 = blockIdx.y * 384;
    float s = 0.f;
    for (int k = k0; k < k0 + 384; ++k)
        s = fmaf(sv[k], W[(size_t)k * QKVW + n], s);
    part[(size_t)blockIdx.y * QKVW + n] = s;
}

__global__ void gemv_reduce(const float* __restrict__ part, const float* __restrict__ bias,
                            float* __restrict__ mod) {
    int n = blockIdx.x * 256 + threadIdx.x;
    float s = bias[n];
    #pragma unroll
    for (int ky = 0; ky < 8; ++ky) s += part[(size_t)ky * QKVW + n];
    mod[n] = s;
}

// LayerNorm + modulate -> bf16 x_mod (tiled layout). 384 threads, 1 row/block.
__global__ __launch_bounds__(384) void ln_mod_kernel(const float* __restrict__ x,
                                                     const float* __restrict__ mod,
                                                     ushort* __restrict__ xmt) {
    int m = blockIdx.x;
    int t = threadIdx.x;
    int lane = t & 63, w = t >> 6;
    const float* xr = x + (size_t)m * HID;
    float4 v0 = *reinterpret_cast<const float4*>(&xr[t * 8]);
    float4 v1 = *reinterpret_cast<const float4*>(&xr[t * 8 + 4]);
    float s = v0.x + v0.y + v0.z + v0.w + v1.x + v1.y + v1.z + v1.w;
    float sq = v0.x * v0.x + v0.y * v0.y + v0.z * v0.z + v0.w * v0.w +
               v1.x * v1.x + v1.y * v1.y + v1.z * v1.z + v1.w * v1.w;
    #pragma unroll
    for (int off = 1; off < 64; off <<= 1) {
        s += __shfl_xor(s, off);
        sq += __shfl_xor(sq, off);
    }
    __shared__ float red[12];
    if (lane == 0) { red[w] = s; red[w + 6] = sq; }
    __syncthreads();
    s = red[0] + red[1] + red[2] + red[3] + red[4] + red[5];
    sq = red[6] + red[7] + red[8] + red[9] + red[10] + red[11];
    float mu = s * (1.f / HID);
    float var = sq * (1.f / HID) - mu * mu;
    float rs = rsqrtf(var + EPSV);
    float vals[8] = {v0.x, v0.y, v0.z, v0.w, v1.x, v1.y, v1.z, v1.w};
    union { ushort u[8]; uint4 q; } pk;
    #pragma unroll
    for (int j = 0; j < 8; ++j) {
        int n = t * 8 + j;
        float y = (vals[j] - mu) * rs * (1.f + mod[HID + n]) + mod[n];
        pk.u[j] = __builtin_bit_cast(ushort, (__bf16)y);
    }
    *reinterpret_cast<uint4*>(&xmt[tpos(m, t * 8, HID >> 6)]) = pk.q;
}

// ---------------- convert f32 [K][N] weights -> tiled bf16 (rows=n, cols=k) --------
__global__ __launch_bounds__(256) void convB_kernel(const float* __restrict__ in,
                                                    ushort* __restrict__ out, int K, int N) {
    __shared__ float tle[64][65];
    int KT = K >> 6;
    int kb = blockIdx.x % KT, nb = blockIdx.x / KT;
    int k0 = kb * 64, n0 = nb * 64;
    int tid = threadIdx.x;
    int rr = tid >> 2, cg = (tid & 3) * 16;
    #pragma unroll
    for (int j = 0; j < 4; ++j) {
        float4 vv = *reinterpret_cast<const float4*>(&in[(size_t)(k0 + rr) * N + n0 + cg + j * 4]);
        tle[rr][cg + j * 4 + 0] = vv.x;
        tle[rr][cg + j * 4 + 1] = vv.y;
        tle[rr][cg + j * 4 + 2] = vv.z;
        tle[rr][cg + j * 4 + 3] = vv.w;
    }
    __syncthreads();
    int nl = tid & 63;
    #pragma unroll
    for (int gg = 0; gg < 2; ++gg) {
        int g = (tid >> 6) + gg * 4;
        union { ushort u[8]; uint4 q; } pk;
        #pragma unroll
        for (int j = 0; j < 8; ++j)
            pk.u[j] = __builtin_bit_cast(ushort, (__bf16)tle[g * 8 + j][nl]);
        *reinterpret_cast<uint4*>(&out[tpos(n0 + nl, k0 + g * 8, KT)]) = pk.q;
    }
}

// ---------------- 8-phase-style 256^2 GEMM (4 phases / K-tile of 64) ----------------
// A tiled [Mtiles][KTtot][img], B tiled [Ntiles][KTtot][img]; both bf16 fragment-block.
// 512 threads = 8 waves (2 wm x 4 wn); per-wave C = 128x64.
// EPI==1: n<9216 -> hqkv f32; else gelu -> a2 tiled bf16 at col 3072+(n-9216)
// EPI==2: partial: outf[(s*SEQ+row)*HID+col] = acc
template <int EPI, int SPLITS>
__global__ __launch_bounds__(512, 2) void gemm8p(
    const ushort* __restrict__ At, const ushort* __restrict__ Bt,
    const float* __restrict__ bias, float* __restrict__ outf, ushort* __restrict__ outb,
    int KTtot, int NTloc, int NTN) {
    // bijective XCD chunk transform (m204)
    int nwg = gridDim.x;
    int q = nwg >> 3, r = nwg & 7;
    int orig = blockIdx.x;
    int xcd = orig & 7;
    int wgid = (xcd < r ? xcd * (q + 1) : r * (q + 1) + (xcd - r) * q) + (orig >> 3);
    int mt = wgid % 5;
    int p = wgid / 5;
    int nt = p % NTN;
    int sp = p / NTN;
    int kOff = sp * NTloc;
    int m0 = mt * 256, n0 = nt * 256;

    __shared__ ushort LA[2][16384];
    __shared__ ushort LB[2][16384];

    int tid = threadIdx.x;
    int lane = tid & 63, wid = tid >> 6;
    int wm = wid >> 2, wn = wid & 3;
    int lr = lane & 15, lg = lane >> 4;

    const ushort* gA = At + (size_t)mt * KTtot * 16384;
    const ushort* gB = Bt + (size_t)nt * KTtot * 16384;

    f32x4 acc[8][4] = {};
    bf16x8_t af[4][2], bf0[2][2], bf1[2][2];

    // stage half-tile h (0=rows/cols 0-127, 1=128-255) of K-tile ktG into buf
    auto stageA = [&](int buf, int ktG, int h) {
        #pragma unroll
        for (int j = 0; j < 2; ++j) {
            int sidx = wid * 2 + j;
            int b = h * 8 + ((sidx & 8) ? 16 + (sidx & 7) : (sidx & 7));
            gload16(gA + (size_t)ktG * 16384 + b * 512 + lane * 8, &LA[buf][b * 512]);
        }
    };
    auto stageB = [&](int buf, int ktG, int h) {
        #pragma unroll
        for (int j = 0; j < 2; ++j) {
            int sidx = wid * 2 + j;
            int b = h * 8 + ((sidx & 8) ? 16 + (sidx & 7) : (sidx & 7));
            gload16(gB + (size_t)ktG * 16384 + b * 512 + lane * 8, &LB[buf][b * 512]);
        }
    };
    auto rdA = [&](int buf, int h) {
        #pragma unroll
        for (int mi = 0; mi < 4; ++mi)
            #pragma unroll
            for (int k = 0; k < 2; ++k)
                af[mi][k] = *reinterpret_cast<const bf16x8_t*>(
                    &LA[buf][(k * 16 + wm * 8 + h * 4 + mi) * 512 + lane * 8]);
    };
    auto rdB = [&](int buf, int v, bf16x8_t bf[2][2]) {
        #pragma unroll
        for (int ni = 0; ni < 2; ++ni)
            #pragma unroll
            for (int k = 0; k < 2; ++k)
                bf[ni][k] = *reinterpret_cast<const bf16x8_t*>(
                    &LB[buf][(k * 16 + wn * 4 + v * 2 + ni) * 512 + lane * 8]);
    };
    auto mm = [&](int h, int v, bf16x8_t bf[2][2]) {
        __builtin_amdgcn_s_setprio(1);
        #pragma unroll
        for (int mi = 0; mi < 4; ++mi)
            #pragma unroll
            for (int ni = 0; ni < 2; ++ni)
                #pragma unroll
                for (int k = 0; k < 2; ++k)
                    acc[h * 4 + mi][v * 2 + ni] = __builtin_amdgcn_mfma_f32_16x16x32_bf16(
                        af[mi][k], bf[ni][k], acc[h * 4 + mi][v * 2 + ni], 0, 0, 0);
        __builtin_amdgcn_s_setprio(0);
    };

    // prologue: BL0, BH0, AL0, AH0, BL1  (5 half-tiles, 10 loads in flight)
    stageB(0, kOff, 0);
    stageB(0, kOff, 1);
    stageA(0, kOff, 0);
    stageA(0, kOff, 1);
    if (NTloc > 1) stageB(1, kOff + 1, 0);

    for (int t = 0; t < NTloc; ++t) {
        int c = t & 1;
        bool pf1 = (t + 1 < NTloc);
        // ---- phase 0: quadrant (h0,v0) ----
        if (pf1) {
            stageB(c ^ 1, kOff + t + 1, 1);                    // B-high(t+1)
            asm volatile("s_waitcnt vmcnt(4)" ::: "memory");   // kt t fully landed
        } else {
            asm volatile("s_waitcnt vmcnt(0)" ::: "memory");
        }
        bar();
        rdA(c, 0);
        rdB(c, 0, bf0);
        mm(0, 0, bf0);
        bar();
        // ---- phase 1: (h0,v1) ----
        rdB(c, 1, bf1);
        if (pf1) stageA(c ^ 1, kOff + t + 1, 0);               // A-low(t+1)
        mm(0, 1, bf1);
        bar();
        // ---- phase 2: (h1,v0) ----
        rdA(c, 1);
        if (pf1) stageA(c ^ 1, kOff + t + 1, 1);               // A-high(t+1)
        mm(1, 0, bf0);
        bar();
        // ---- phase 3: (h1,v1) ----
        if (t + 2 < NTloc) stageB(c, kOff + t + 2, 0);         // B-low(t+2) into cur buf
        mm(1, 1, bf1);
        bar();
    }

    #pragma unroll
    for (int mi8 = 0; mi8 < 8; ++mi8) {
        #pragma unroll
        for (int nj = 0; nj < 4; ++nj) {
            int col = n0 + wn * 64 + nj * 16 + lr;
            #pragma unroll
            for (int rr2 = 0; rr2 < 4; ++rr2) {
                int row = m0 + wm * 128 + mi8 * 16 + lg * 4 + rr2;
                float val = acc[mi8][nj][rr2];
                if (EPI == 1) {
                    val += bias[col];
                    if (n0 < QKVW) {
                        outf[(size_t)row * QKVW + col] = val;
                    } else {
                        float u = 0.7978845608028654f * (val + 0.044715f * val * val * val);
                        float g = val / (1.f + __expf(-2.f * u));
                        outb[tpos(row, HID + (col - QKVW), A2W >> 6)] =
                            __builtin_bit_cast(ushort, (__bf16)g);
                    }
                } else {
                    outf[(size_t)(sp * SEQ + row) * HID + col] = val;
                }
            }
        }
    }
}

// out = x + (sum_s part[s] + bias) * gate
__global__ __launch_bounds__(256) void ksplit_reduce(const float* __restrict__ part,
                                                     const float* __restrict__ x,
                                                     const float* __restrict__ bias,
                                                     const float* __restrict__ gate,
                                                     float* __restrict__ out) {
    int i = blockIdx.x * 256 + threadIdx.x;
    int col = (i % (HID / 4)) * 4;
    f32x4 a = *reinterpret_cast<const f32x4*>(&part[(size_t)i * 4]);
    #pragma unroll
    for (int s = 1; s < 4; ++s) {
        f32x4 p = *reinterpret_cast<const f32x4*>(&part[(size_t)s * SEQ * HID + (size_t)i * 4]);
        #pragma unroll
        for (int c = 0; c < 4; ++c) a[c] += p[c];
    }
    f32x4 xv = *reinterpret_cast<const f32x4*>(&x[(size_t)i * 4]);
    f32x4 bv = *reinterpret_cast<const f32x4*>(&bias[col]);
    f32x4 gv = *reinterpret_cast<const f32x4*>(&gate[col]);
    f32x4 o;
    #pragma unroll
    for (int c = 0; c < 4; ++c) o[c] = xv[c] + (a[c] + bv[c]) * gv[c];
    *reinterpret_cast<f32x4*>(&out[(size_t)i * 4]) = o;
}

// ---------------- qkv post: RMSNorm(q,k) + RoPE(img rows) -> (h,l,d) bf16 ----------------
__global__ __launch_bounds__(256) void qkv_post(const float* __restrict__ h,
                                                const float* __restrict__ fc,
                                                const float* __restrict__ fs,
                                                const float* __restrict__ qn,
                                                const float* __restrict__ kn,
                                                __bf16* __restrict__ qb,
                                                __bf16* __restrict__ kb,
                                                __bf16* __restrict__ vb) {
    int m = blockIdx.x;
    int lane = threadIdx.x & 63, w = threadIdx.x >> 6;
    for (int rr = w; rr < 72; rr += 4) {
        int s = rr / 24, hd = rr % 24;
        const float* src = h + (size_t)m * QKVW + s * HID + hd * HD;
        float2 xv = *reinterpret_cast<const float2*>(&src[2 * lane]);
        float x0 = xv.x, x1 = xv.y;
        if (s < 2) {
            float ss = x0 * x0 + x1 * x1;
            #pragma unroll
            for (int off = 1; off < 64; off <<= 1) ss += __shfl_xor(ss, off);
            float rs = rsqrtf(ss * (1.f / HD) + EPSV);
            const float* nw = (s == 0) ? qn : kn;
            x0 *= rs * nw[2 * lane];
            x1 *= rs * nw[2 * lane + 1];
            if (m < IMG) {
                float c0 = fc[m * HD + 2 * lane], c1 = fc[m * HD + 2 * lane + 1];
                float s0 = fs[m * HD + 2 * lane], s1 = fs[m * HD + 2 * lane + 1];
                float r0 = x0 * c0 - x1 * s0;
                float r1 = x1 * c1 + x0 * s1;
                x0 = r0; x1 = r1;
            }
        }
        __bf16* dst = ((s == 0) ? qb : (s == 1) ? kb : vb) + (size_t)hd * SEQ * HD + (size_t)m * HD + 2 * lane;
        ushort u0 = __builtin_bit_cast(ushort, (__bf16)x0);
        ushort u1 = __builtin_bit_cast(ushort, (__bf16)x1);
        *reinterpret_cast<uint*>(dst) = (uint)u0 | ((uint)u1 << 16);
    }
}

// ---------------- flash attention (writes tiled a2) ----------------
__global__ __launch_bounds__(256) void attn_kernel(const __bf16* __restrict__ qb,
                                                   const __bf16* __restrict__ kb,
                                                   const __bf16* __restrict__ vb,
                                                   ushort* __restrict__ a2) {
    int head = blockIdx.y;
    int tid = threadIdx.x;
    int lane = tid & 63, w = tid >> 6;
    int lr = lane & 15, lg = lane >> 4;
    int q0 = blockIdx.x * 64 + w * 16;
    const __bf16* Q = qb + (size_t)head * SEQ * HD;
    const __bf16* Kp = kb + (size_t)head * SEQ * HD;
    const __bf16* Vp = vb + (size_t)head * SEQ * HD;

    bf16x8_t qf[4];
    #pragma unroll
    for (int kc = 0; kc < 4; ++kc)
        qf[kc] = *reinterpret_cast<const bf16x8_t*>(&Q[(size_t)(q0 + lr) * HD + kc * 32 + lg * 8]);

    __shared__ alignas(16) __bf16 Kl[32][136];
    __shared__ alignas(16) __bf16 Vl[32][136];
    __shared__ float Pl[4][32][16];

    float m_run = -1e30f, l_run = 0.f;
    f32x4 of[8] = {};
    const float sm_scale = 0.08838834764831845f;

    for (int kv0 = 0; kv0 < SEQ; kv0 += 32) {
        #pragma unroll
        for (int cc = 0; cc < 2; ++cc) {
            int c = tid + cc * 256;
            int row = c >> 4, off = (c & 15) * 8;
            *reinterpret_cast<bf16x8_t*>(&Kl[row][off]) =
                *reinterpret_cast<const bf16x8_t*>(&Kp[(size_t)(kv0 + row) * HD + off]);
            *reinterpret_cast<bf16x8_t*>(&Vl[row][off]) =
                *reinterpret_cast<const bf16x8_t*>(&Vp[(size_t)(kv0 + row) * HD + off]);
        }
        __syncthreads();

        f32x4 st[2] = {};
        #pragma unroll
        for (int h = 0; h < 2; ++h)
            #pragma unroll
            for (int kc = 0; kc < 4; ++kc) {
                bf16x8_t kf = *reinterpret_cast<const bf16x8_t*>(&Kl[h * 16 + lr][kc * 32 + lg * 8]);
                st[h] = __builtin_amdgcn_mfma_f32_16x16x32_bf16(kf, qf[kc], st[h], 0, 0, 0);
            }
        float sarr[8];
        #pragma unroll
        for (int h = 0; h < 2; ++h)
            #pragma unroll
            for (int r = 0; r < 4; ++r) sarr[h * 4 + r] = st[h][r] * sm_scale;

        float mloc = sarr[0];
        #pragma unroll
        for (int i = 1; i < 8; ++i) mloc = fmaxf(mloc, sarr[i]);
        mloc = fmaxf(mloc, __shfl_xor(mloc, 16));
        mloc = fmaxf(mloc, __shfl_xor(mloc, 32));
        float m_new = fmaxf(m_run, mloc);
        float alpha = expf(m_run - m_new);
        float pv[8], psum = 0.f;
        #pragma unroll
        for (int i = 0; i < 8; ++i) { pv[i] = expf(sarr[i] - m_new); psum += pv[i]; }
        psum += __shfl_xor(psum, 16);
        psum += __shfl_xor(psum, 32);
        l_run = l_run * alpha + psum;
        m_run = m_new;

        #pragma unroll
        for (int h = 0; h < 2; ++h)
            #pragma unroll
            for (int r = 0; r < 4; ++r) Pl[w][h * 16 + lg * 4 + r][lr] = pv[h * 4 + r];
        bf16x8_t pa;
        #pragma unroll
        for (int j = 0; j < 8; ++j) pa[j] = (__bf16)Pl[w][lg * 8 + j][lr];

        float alr[4];
        #pragma unroll
        for (int r = 0; r < 4; ++r) alr[r] = __shfl(alpha, lg * 4 + r);

        #pragma unroll
        for (int db = 0; db < 8; ++db) {
            #pragma unroll
            for (int r = 0; r < 4; ++r) of[db][r] *= alr[r];
            bf16x8_t vv;
            #pragma unroll
            for (int j = 0; j < 8; ++j) vv[j] = Vl[lg * 8 + j][db * 16 + lr];
            of[db] = __builtin_amdgcn_mfma_f32_16x16x32_bf16(pa, vv, of[db], 0, 0, 0);
        }
        __syncthreads();
    }

    float lr4[4];
    #pragma unroll
    for (int r = 0; r < 4; ++r) lr4[r] = __shfl(l_run, lg * 4 + r);
    #pragma unroll
    for (int db = 0; db < 8; ++db)
        #pragma unroll
        for (int r = 0; r < 4; ++r) {
            int row = q0 + lg * 4 + r;
            int col = head * HD + db * 16 + lr;
            a2[tpos(row, col, A2W >> 6)] =
                __builtin_bit_cast(ushort, (__bf16)(of[db][r] / lr4[r]));
        }
}

// ---------------- launch ----------------
extern "C" void kernel_launch(void* const* d_in, const int* in_sizes, int n_in,
                              void* d_out, int out_size, void* d_ws, size_t ws_size,
                              hipStream_t stream) {
    const float* x = (const float*)d_in[0];
    const float* vec = (const float*)d_in[1];
    const float* fc = (const float*)d_in[2];
    const float* fs = (const float*)d_in[3];
    const float* mod_w = (const float*)d_in[4];
    const float* mod_b = (const float*)d_in[5];
    const float* w1 = (const float*)d_in[6];
    const float* b1 = (const float*)d_in[7];
    const float* w2 = (const float*)d_in[8];
    const float* b2 = (const float*)d_in[9];
    const float* qn = (const float*)d_in[10];
    const float* kn = (const float*)d_in[11];
    float* out = (float*)d_out;

    char* ws = (char*)d_ws;
    size_t off = 0;
    float* sv = (float*)(ws + off); off += 3072 * 4;
    float* mod = (float*)(ws + off); off += 9216 * 4;
    float* part = (float*)(ws + off); off += 8 * 9216 * 4;
    off = (off + 255) & ~(size_t)255;
    ushort* xmt = (ushort*)(ws + off); off += (size_t)SEQ * HID * 2;      // tiled x_mod
    off = (off + 255) & ~(size_t)255;
    float* hqkv = (float*)(ws + off); off += (size_t)SEQ * QKVW * 4;
    __bf16* qb = (__bf16*)(ws + off); off += (size_t)NHEADS * SEQ * HD * 2;
    __bf16* kb = (__bf16*)(ws + off); off += (size_t)NHEADS * SEQ * HD * 2;
    __bf16* vb = (__bf16*)(ws + off); off += (size_t)NHEADS * SEQ * HD * 2;
    off = (off + 255) & ~(size_t)255;
    ushort* a2t = (ushort*)(ws + off); off += (size_t)SEQ * A2W * 2;      // tiled [attn|gelu]
    // k-split partials (4*SEQ*HID f32 = 62.9MB) alias hqkv+qb+kb (dead before gemm2)
    float* part2 = hqkv;

    off = (off + 255) & ~(size_t)255;
    ushort* w1b = (ushort*)(ws + off);   // tiled bf16 w1 [N1 x HID]; w2b aliases (dead after gemm1)
    ushort* w2b = w1b;

    silu_kernel<<<12, 256, 0, stream>>>(vec, sv);
    gemv_part<<<dim3(36, 8), 256, 0, stream>>>(sv, mod_w, part);
    gemv_reduce<<<36, 256, 0, stream>>>(part, mod_b, mod);
    ln_mod_kernel<<<SEQ, 384, 0, stream>>>(x, mod, xmt);

    convB_kernel<<<(HID / 64) * (N1 / 64), 256, 0, stream>>>(w1, w1b, HID, N1);
    gemm8p<1, 1><<<5 * (N1 / 256), 512, 0, stream>>>(xmt, w1b, b1, hqkv, a2t,
                                                     HID / 64, HID / 64, N1 / 256);
    convB_kernel<<<(A2W / 64) * (HID / 64), 256, 0, stream>>>(w2, w2b, A2W, HID);
    qkv_post<<<SEQ, 256, 0, stream>>>(hqkv, fc, fs, qn, kn, qb, kb, vb);
    attn_kernel<<<dim3(SEQ / 64, NHEADS), 256, 0, stream>>>(qb, kb, vb, a2t);
    gemm8p<2, 4><<<4 * 5 * (HID / 256), 512, 0, stream>>>(a2t, w2b, nullptr, part2, nullptr,
                                                          A2W / 64, A2W / 64 / 4, HID / 256);
    ksplit_reduce<<<SEQ * HID / 1024, 256, 0, stream>>>(part2, x, b2, mod + 2 * HID, out);
}

// Round 6
// 653.668 us; speedup vs baseline: 1.7648x; 1.0471x over previous
//
#include <hip/hip_runtime.h>
#include <cstdint>
#include <cstddef>

typedef __bf16 bf16x8_t __attribute__((ext_vector_type(8)));
typedef float f32x4 __attribute__((ext_vector_type(4)));

#define HID 3072
#define NHEADS 24
#define HD 128
#define MLP 12288
#define SEQ 1280
#define IMG 1024
#define N1 21504   /* 3*HID + MLP */
#define QKVW 9216  /* 3*HID */
#define A2W 15360  /* HID + MLP */
#define EPSV 1e-6f

// Tiled bf16 operand layout ("fragment-block" order):
// element (row, col) of a [rows][K] operand lives at:
//   tile (row>>8, col>>6) -> 16384-elem image of 32 blocks x 512 elems:
//   block = ((col>>5)&1)*16 + ((row>>4)&15)         (k32 , row16)
//   slot  = (row&15) + ((col>>3)&3)*16              (lane = lr + lg*16)
//   elem  = block*512 + slot*8 + (col&7)
// One block = 1024B = one wave ds_read_b128 / global_load_lds_dwordx4 unit.
__device__ __forceinline__ size_t tpos(int row, int col, int KT) {
    return ((size_t)(row >> 8) * KT + (col >> 6)) * 16384
         + (size_t)(((((col >> 5) & 1) << 4) + ((row >> 4) & 15)) * 512
                    + (((row & 15) + (((col >> 3) & 3) << 4)) << 3) + (col & 7));
}

// async global->LDS, 16B per lane (HW adds lane*16 to wave-uniform LDS base)
__device__ __forceinline__ void gload16(const void* g, void* l) {
    __builtin_amdgcn_global_load_lds(
        (const __attribute__((address_space(1))) unsigned int*)g,
        (__attribute__((address_space(3))) unsigned int*)l, 16, 0, 0);
}

__device__ __forceinline__ void bar() {
    asm volatile("" ::: "memory");
    __builtin_amdgcn_s_barrier();
    asm volatile("" ::: "memory");
}

// ---------------- small kernels ----------------
__global__ void silu_kernel(const float* __restrict__ v, float* __restrict__ sv) {
    int i = blockIdx.x * 256 + threadIdx.x;
    float x = v[i];
    sv[i] = x / (1.f + expf(-x));
}

__global__ void gemv_part(const float* __restrict__ sv, const float* __restrict__ W,
                          float* __restrict__ part) {
    int n = blockIdx.x * 256 + threadIdx.x;
    int k0 = blockIdx.y * 384;
    float s = 0.f;
    for (int k = k0; k < k0 + 384; ++k)
        s = fmaf(sv[k], W[(size_t)k * QKVW + n], s);
    part[(size_t)blockIdx.y * QKVW + n] = s;
}

__global__ void gemv_reduce(const float* __restrict__ part, const float* __restrict__ bias,
                            float* __restrict__ mod) {
    int n = blockIdx.x * 256 + threadIdx.x;
    float s = bias[n];
    #pragma unroll
    for (int ky = 0; ky < 8; ++ky) s += part[(size_t)ky * QKVW + n];
    mod[n] = s;
}

// LayerNorm + modulate -> bf16 x_mod (tiled layout). 384 threads, 1 row/block.
__global__ __launch_bounds__(384) void ln_mod_kernel(const float* __restrict__ x,
                                                     const float* __restrict__ mod,
                                                     ushort* __restrict__ xmt) {
    int m = blockIdx.x;
    int t = threadIdx.x;
    int lane = t & 63, w = t >> 6;
    const float* xr = x + (size_t)m * HID;
    float4 v0 = *reinterpret_cast<const float4*>(&xr[t * 8]);
    float4 v1 = *reinterpret_cast<const float4*>(&xr[t * 8 + 4]);
    float s = v0.x + v0.y + v0.z + v0.w + v1.x + v1.y + v1.z + v1.w;
    float sq = v0.x * v0.x + v0.y * v0.y + v0.z * v0.z + v0.w * v0.w +
               v1.x * v1.x + v1.y * v1.y + v1.z * v1.z + v1.w * v1.w;
    #pragma unroll
    for (int off = 1; off < 64; off <<= 1) {
        s += __shfl_xor(s, off);
        sq += __shfl_xor(sq, off);
    }
    __shared__ float red[12];
    if (lane == 0) { red[w] = s; red[w + 6] = sq; }
    __syncthreads();
    s = red[0] + red[1] + red[2] + red[3] + red[4] + red[5];
    sq = red[6] + red[7] + red[8] + red[9] + red[10] + red[11];
    float mu = s * (1.f / HID);
    float var = sq * (1.f / HID) - mu * mu;
    float rs = rsqrtf(var + EPSV);
    float vals[8] = {v0.x, v0.y, v0.z, v0.w, v1.x, v1.y, v1.z, v1.w};
    union { ushort u[8]; uint4 q; } pk;
    #pragma unroll
    for (int j = 0; j < 8; ++j) {
        int n = t * 8 + j;
        float y = (vals[j] - mu) * rs * (1.f + mod[HID + n]) + mod[n];
        pk.u[j] = __builtin_bit_cast(ushort, (__bf16)y);
    }
    *reinterpret_cast<uint4*>(&xmt[tpos(m, t * 8, HID >> 6)]) = pk.q;
}

// ---------------- convert f32 [K][N] weights -> tiled bf16 (rows=n, cols=k) --------
__global__ __launch_bounds__(256) void convB_kernel(const float* __restrict__ in,
                                                    ushort* __restrict__ out, int K, int N) {
    __shared__ float tle[64][65];
    int KT = K >> 6;
    int kb = blockIdx.x % KT, nb = blockIdx.x / KT;
    int k0 = kb * 64, n0 = nb * 64;
    int tid = threadIdx.x;
    int rr = tid >> 2, cg = (tid & 3) * 16;
    #pragma unroll
    for (int j = 0; j < 4; ++j) {
        float4 vv = *reinterpret_cast<const float4*>(&in[(size_t)(k0 + rr) * N + n0 + cg + j * 4]);
        tle[rr][cg + j * 4 + 0] = vv.x;
        tle[rr][cg + j * 4 + 1] = vv.y;
        tle[rr][cg + j * 4 + 2] = vv.z;
        tle[rr][cg + j * 4 + 3] = vv.w;
    }
    __syncthreads();
    int nl = tid & 63;
    #pragma unroll
    for (int gg = 0; gg < 2; ++gg) {
        int g = (tid >> 6) + gg * 4;
        union { ushort u[8]; uint4 q; } pk;
        #pragma unroll
        for (int j = 0; j < 8; ++j)
            pk.u[j] = __builtin_bit_cast(ushort, (__bf16)tle[g * 8 + j][nl]);
        *reinterpret_cast<uint4*>(&out[tpos(n0 + nl, k0 + g * 8, KT)]) = pk.q;
    }
}

// ---------------- 256^2 GEMM, 4 phases/K-tile, reads pipelined 1 phase ahead --------
// A tiled [Mtiles][KTtot][img], B tiled [Ntiles][KTtot][img]; both bf16 fragment-block.
// 512 threads = 8 waves (2 wm x 4 wn); per-wave C = 128x64.
// EPI==1: n<9216 -> hqkv f32; else gelu -> a2 tiled bf16 at col 3072+(n-9216)
// EPI==2: partial: outf[(s*SEQ+row)*HID+col] = acc
template <int EPI, int SPLITS>
__global__ __launch_bounds__(512, 2) void gemm8p(
    const ushort* __restrict__ At, const ushort* __restrict__ Bt,
    const float* __restrict__ bias, float* __restrict__ outf, ushort* __restrict__ outb,
    int KTtot, int NTloc, int NTN) {
    // bijective XCD chunk transform (m204)
    int nwg = gridDim.x;
    int q = nwg >> 3, r = nwg & 7;
    int orig = blockIdx.x;
    int xcd = orig & 7;
    int wgid = (xcd < r ? xcd * (q + 1) : r * (q + 1) + (xcd - r) * q) + (orig >> 3);
    int mt = wgid % 5;
    int p = wgid / 5;
    int nt = p % NTN;
    int sp = p / NTN;
    int kOff = sp * NTloc;
    int m0 = mt * 256, n0 = nt * 256;

    __shared__ ushort LA[2][16384];
    __shared__ ushort LB[2][16384];

    int tid = threadIdx.x;
    int lane = tid & 63, wid = tid >> 6;
    int wm = wid >> 2, wn = wid & 3;
    int lr = lane & 15, lg = lane >> 4;

    const ushort* gA = At + (size_t)mt * KTtot * 16384;
    const ushort* gB = Bt + (size_t)nt * KTtot * 16384;

    f32x4 acc[8][4] = {};
    bf16x8_t af0[4][2], af1[4][2], bf0[2][2], bf1[2][2];

    // stage one full 256x64 operand tile: 8 waves x 4 blocks x 1KB
    auto stage = [&](ushort (*L)[16384], int buf, const ushort* g, int ktG) {
        #pragma unroll
        for (int j = 0; j < 4; ++j) {
            int b = wid * 4 + j;
            gload16(g + (size_t)ktG * 16384 + b * 512 + lane * 8, &L[buf][b * 512]);
        }
    };
    auto rdA = [&](int buf, int h, bf16x8_t (&af)[4][2]) {
        #pragma unroll
        for (int mi = 0; mi < 4; ++mi)
            #pragma unroll
            for (int k = 0; k < 2; ++k)
                af[mi][k] = *reinterpret_cast<const bf16x8_t*>(
                    &LA[buf][(k * 16 + wm * 8 + h * 4 + mi) * 512 + lane * 8]);
    };
    auto rdB = [&](int buf, int v, bf16x8_t (&bf)[2][2]) {
        #pragma unroll
        for (int ni = 0; ni < 2; ++ni)
            #pragma unroll
            for (int k = 0; k < 2; ++k)
                bf[ni][k] = *reinterpret_cast<const bf16x8_t*>(
                    &LB[buf][(k * 16 + wn * 4 + v * 2 + ni) * 512 + lane * 8]);
    };
    auto mmq = [&](bf16x8_t (&af)[4][2], bf16x8_t (&bf)[2][2], int h, int v) {
        __builtin_amdgcn_s_setprio(1);
        #pragma unroll
        for (int mi = 0; mi < 4; ++mi)
            #pragma unroll
            for (int ni = 0; ni < 2; ++ni)
                #pragma unroll
                for (int k = 0; k < 2; ++k)
                    acc[h * 4 + mi][v * 2 + ni] = __builtin_amdgcn_mfma_f32_16x16x32_bf16(
                        af[mi][k], bf[ni][k], acc[h * 4 + mi][v * 2 + ni], 0, 0, 0);
        __builtin_amdgcn_s_setprio(0);
    };

    // prologue: stage tiles 0 and 1, wait for tile 0, preload its first frags
    stage(LA, 0, gA, kOff);
    stage(LB, 0, gB, kOff);
    stage(LA, 1, gA, kOff + 1);
    stage(LB, 1, gB, kOff + 1);
    asm volatile("s_waitcnt vmcnt(8)" ::: "memory");
    bar();
    rdA(0, 0, af0);
    rdB(0, 0, bf0);

    for (int t = 0; t < NTloc; ++t) {
        int c = t & 1;
        // ph0: mm(0,0) ; read bf1(t)
        rdB(c, 1, bf1);
        mmq(af0, bf0, 0, 0);
        bar();
        // ph1: mm(0,1) ; read af1(t)
        rdA(c, 1, af1);
        mmq(af0, bf1, 0, 1);
        bar();
        // ph2: mm(1,0) ; stage A(t+2) ; counted vmcnt guarantees tile t+1 landed
        if (t + 2 < NTloc) stage(LA, c, gA, kOff + t + 2);
        mmq(af1, bf0, 1, 0);
        if (t + 1 < NTloc) {
            if (t + 2 < NTloc) asm volatile("s_waitcnt vmcnt(4)" ::: "memory");
            else               asm volatile("s_waitcnt vmcnt(0)" ::: "memory");
        }
        bar();
        // ph3: mm(1,1) ; read af0/bf0(t+1) from other buffer ; stage B(t+2)
        if (t + 1 < NTloc) {
            rdA(c ^ 1, 0, af0);
            rdB(c ^ 1, 0, bf0);
        }
        if (t + 2 < NTloc) stage(LB, c, gB, kOff + t + 2);
        mmq(af1, bf1, 1, 1);
        bar();
    }

    #pragma unroll
    for (int mi8 = 0; mi8 < 8; ++mi8) {
        #pragma unroll
        for (int nj = 0; nj < 4; ++nj) {
            int col = n0 + wn * 64 + nj * 16 + lr;
            #pragma unroll
            for (int rr2 = 0; rr2 < 4; ++rr2) {
                int row = m0 + wm * 128 + mi8 * 16 + lg * 4 + rr2;
                float val = acc[mi8][nj][rr2];
                if (EPI == 1) {
                    val += bias[col];
                    if (n0 < QKVW) {
                        outf[(size_t)row * QKVW + col] = val;
                    } else {
                        float u = 0.7978845608028654f * (val + 0.044715f * val * val * val);
                        float g = val / (1.f + __expf(-2.f * u));
                        outb[tpos(row, HID + (col - QKVW), A2W >> 6)] =
                            __builtin_bit_cast(ushort, (__bf16)g);
                    }
                } else {
                    outf[(size_t)(sp * SEQ + row) * HID + col] = val;
                }
            }
        }
    }
}

// out = x + (sum_s part[s] + bias) * gate
__global__ __launch_bounds__(256) void ksplit_reduce(const float* __restrict__ part,
                                                     const float* __restrict__ x,
                                                     const float* __restrict__ bias,
                                                     const float* __restrict__ gate,
                                                     float* __restrict__ out) {
    int i = blockIdx.x * 256 + threadIdx.x;
    int col = (i % (HID / 4)) * 4;
    f32x4 a = *reinterpret_cast<const f32x4*>(&part[(size_t)i * 4]);
    #pragma unroll
    for (int s = 1; s < 4; ++s) {
        f32x4 p = *reinterpret_cast<const f32x4*>(&part[(size_t)s * SEQ * HID + (size_t)i * 4]);
        #pragma unroll
        for (int c = 0; c < 4; ++c) a[c] += p[c];
    }
    f32x4 xv = *reinterpret_cast<const f32x4*>(&x[(size_t)i * 4]);
    f32x4 bv = *reinterpret_cast<const f32x4*>(&bias[col]);
    f32x4 gv = *reinterpret_cast<const f32x4*>(&gate[col]);
    f32x4 o;
    #pragma unroll
    for (int c = 0; c < 4; ++c) o[c] = xv[c] + (a[c] + bv[c]) * gv[c];
    *reinterpret_cast<f32x4*>(&out[(size_t)i * 4]) = o;
}

// ---------------- qkv post: RMSNorm(q,k) + RoPE(img rows) -> (h,l,d) bf16 ----------------
__global__ __launch_bounds__(256) void qkv_post(const float* __restrict__ h,
                                                const float* __restrict__ fc,
                                                const float* __restrict__ fs,
                                                const float* __restrict__ qn,
                                                const float* __restrict__ kn,
                                                __bf16* __restrict__ qb,
                                                __bf16* __restrict__ kb,
                                                __bf16* __restrict__ vb) {
    int m = blockIdx.x;
    int lane = threadIdx.x & 63, w = threadIdx.x >> 6;
    for (int rr = w; rr < 72; rr += 4) {
        int s = rr / 24, hd = rr % 24;
        const float* src = h + (size_t)m * QKVW + s * HID + hd * HD;
        float2 xv = *reinterpret_cast<const float2*>(&src[2 * lane]);
        float x0 = xv.x, x1 = xv.y;
        if (s < 2) {
            float ss = x0 * x0 + x1 * x1;
            #pragma unroll
            for (int off = 1; off < 64; off <<= 1) ss += __shfl_xor(ss, off);
            float rs = rsqrtf(ss * (1.f / HD) + EPSV);
            const float* nw = (s == 0) ? qn : kn;
            x0 *= rs * nw[2 * lane];
            x1 *= rs * nw[2 * lane + 1];
            if (m < IMG) {
                float c0 = fc[m * HD + 2 * lane], c1 = fc[m * HD + 2 * lane + 1];
                float s0 = fs[m * HD + 2 * lane], s1 = fs[m * HD + 2 * lane + 1];
                float r0 = x0 * c0 - x1 * s0;
                float r1 = x1 * c1 + x0 * s1;
                x0 = r0; x1 = r1;
            }
        }
        __bf16* dst = ((s == 0) ? qb : (s == 1) ? kb : vb) + (size_t)hd * SEQ * HD + (size_t)m * HD + 2 * lane;
        ushort u0 = __builtin_bit_cast(ushort, (__bf16)x0);
        ushort u1 = __builtin_bit_cast(ushort, (__bf16)x1);
        *reinterpret_cast<uint*>(dst) = (uint)u0 | ((uint)u1 << 16);
    }
}

// ---------------- flash attention (writes tiled a2) ----------------
__global__ __launch_bounds__(256) void attn_kernel(const __bf16* __restrict__ qb,
                                                   const __bf16* __restrict__ kb,
                                                   const __bf16* __restrict__ vb,
                                                   ushort* __restrict__ a2) {
    int head = blockIdx.y;
    int tid = threadIdx.x;
    int lane = tid & 63, w = tid >> 6;
    int lr = lane & 15, lg = lane >> 4;
    int q0 = blockIdx.x * 64 + w * 16;
    const __bf16* Q = qb + (size_t)head * SEQ * HD;
    const __bf16* Kp = kb + (size_t)head * SEQ * HD;
    const __bf16* Vp = vb + (size_t)head * SEQ * HD;

    bf16x8_t qf[4];
    #pragma unroll
    for (int kc = 0; kc < 4; ++kc)
        qf[kc] = *reinterpret_cast<const bf16x8_t*>(&Q[(size_t)(q0 + lr) * HD + kc * 32 + lg * 8]);

    __shared__ alignas(16) __bf16 Kl[32][136];
    __shared__ alignas(16) __bf16 Vl[32][136];
    __shared__ float Pl[4][32][16];

    float m_run = -1e30f, l_run = 0.f;
    f32x4 of[8] = {};
    const float sm_scale = 0.08838834764831845f;

    for (int kv0 = 0; kv0 < SEQ; kv0 += 32) {
        #pragma unroll
        for (int cc = 0; cc < 2; ++cc) {
            int c = tid + cc * 256;
            int row = c >> 4, off = (c & 15) * 8;
            *reinterpret_cast<bf16x8_t*>(&Kl[row][off]) =
                *reinterpret_cast<const bf16x8_t*>(&Kp[(size_t)(kv0 + row) * HD + off]);
            *reinterpret_cast<bf16x8_t*>(&Vl[row][off]) =
                *reinterpret_cast<const bf16x8_t*>(&Vp[(size_t)(kv0 + row) * HD + off]);
        }
        __syncthreads();

        f32x4 st[2] = {};
        #pragma unroll
        for (int h = 0; h < 2; ++h)
            #pragma unroll
            for (int kc = 0; kc < 4; ++kc) {
                bf16x8_t kf = *reinterpret_cast<const bf16x8_t*>(&Kl[h * 16 + lr][kc * 32 + lg * 8]);
                st[h] = __builtin_amdgcn_mfma_f32_16x16x32_bf16(kf, qf[kc], st[h], 0, 0, 0);
            }
        float sarr[8];
        #pragma unroll
        for (int h = 0; h < 2; ++h)
            #pragma unroll
            for (int r = 0; r < 4; ++r) sarr[h * 4 + r] = st[h][r] * sm_scale;

        float mloc = sarr[0];
        #pragma unroll
        for (int i = 1; i < 8; ++i) mloc = fmaxf(mloc, sarr[i]);
        mloc = fmaxf(mloc, __shfl_xor(mloc, 16));
        mloc = fmaxf(mloc, __shfl_xor(mloc, 32));
        float m_new = fmaxf(m_run, mloc);
        float alpha = expf(m_run - m_new);
        float pv[8], psum = 0.f;
        #pragma unroll
        for (int i = 0; i < 8; ++i) { pv[i] = expf(sarr[i] - m_new); psum += pv[i]; }
        psum += __shfl_xor(psum, 16);
        psum += __shfl_xor(psum, 32);
        l_run = l_run * alpha + psum;
        m_run = m_new;

        #pragma unroll
        for (int h = 0; h < 2; ++h)
            #pragma unroll
            for (int r = 0; r < 4; ++r) Pl[w][h * 16 + lg * 4 + r][lr] = pv[h * 4 + r];
        bf16x8_t pa;
        #pragma unroll
        for (int j = 0; j < 8; ++j) pa[j] = (__bf16)Pl[w][lg * 8 + j][lr];

        float alr[4];
        #pragma unroll
        for (int r = 0; r < 4; ++r) alr[r] = __shfl(alpha, lg * 4 + r);

        #pragma unroll
        for (int db = 0; db < 8; ++db) {
            #pragma unroll
            for (int r = 0; r < 4; ++r) of[db][r] *= alr[r];
            bf16x8_t vv;
            #pragma unroll
            for (int j = 0; j < 8; ++j) vv[j] = Vl[lg * 8 + j][db * 16 + lr];
            of[db] = __builtin_amdgcn_mfma_f32_16x16x32_bf16(pa, vv, of[db], 0, 0, 0);
        }
        __syncthreads();
    }

    float lr4[4];
    #pragma unroll
    for (int r = 0; r < 4; ++r) lr4[r] = __shfl(l_run, lg * 4 + r);
    #pragma unroll
    for (int db = 0; db < 8; ++db)
        #pragma unroll
        for (int r = 0; r < 4; ++r) {
            int row = q0 + lg * 4 + r;
            int col = head * HD + db * 16 + lr;
            a2[tpos(row, col, A2W >> 6)] =
                __builtin_bit_cast(ushort, (__bf16)(of[db][r] / lr4[r]));
        }
}

// ---------------- launch ----------------
extern "C" void kernel_launch(void* const* d_in, const int* in_sizes, int n_in,
                              void* d_out, int out_size, void* d_ws, size_t ws_size,
                              hipStream_t stream) {
    const float* x = (const float*)d_in[0];
    const float* vec = (const float*)d_in[1];
    const float* fc = (const float*)d_in[2];
    const float* fs = (const float*)d_in[3];
    const float* mod_w = (const float*)d_in[4];
    const float* mod_b = (const float*)d_in[5];
    const float* w1 = (const float*)d_in[6];
    const float* b1 = (const float*)d_in[7];
    const float* w2 = (const float*)d_in[8];
    const float* b2 = (const float*)d_in[9];
    const float* qn = (const float*)d_in[10];
    const float* kn = (const float*)d_in[11];
    float* out = (float*)d_out;

    char* ws = (char*)d_ws;
    size_t off = 0;
    float* sv = (float*)(ws + off); off += 3072 * 4;
    float* mod = (float*)(ws + off); off += 9216 * 4;
    float* part = (float*)(ws + off); off += 8 * 9216 * 4;
    off = (off + 255) & ~(size_t)255;
    ushort* xmt = (ushort*)(ws + off); off += (size_t)SEQ * HID * 2;      // tiled x_mod
    off = (off + 255) & ~(size_t)255;
    float* hqkv = (float*)(ws + off); off += (size_t)SEQ * QKVW * 4;
    __bf16* qb = (__bf16*)(ws + off); off += (size_t)NHEADS * SEQ * HD * 2;
    __bf16* kb = (__bf16*)(ws + off); off += (size_t)NHEADS * SEQ * HD * 2;
    __bf16* vb = (__bf16*)(ws + off); off += (size_t)NHEADS * SEQ * HD * 2;
    off = (off + 255) & ~(size_t)255;
    ushort* a2t = (ushort*)(ws + off); off += (size_t)SEQ * A2W * 2;      // tiled [attn|gelu]
    // k-split partials (4*SEQ*HID f32 = 62.9MB) alias hqkv+qb+kb (dead before gemm2)
    float* part2 = hqkv;

    off = (off + 255) & ~(size_t)255;
    ushort* w1b = (ushort*)(ws + off);   // tiled bf16 w1 [N1 x HID]; w2b aliases (dead after gemm1)
    ushort* w2b = w1b;

    silu_kernel<<<12, 256, 0, stream>>>(vec, sv);
    gemv_part<<<dim3(36, 8), 256, 0, stream>>>(sv, mod_w, part);
    gemv_reduce<<<36, 256, 0, stream>>>(part, mod_b, mod);
    ln_mod_kernel<<<SEQ, 384, 0, stream>>>(x, mod, xmt);

    convB_kernel<<<(HID / 64) * (N1 / 64), 256, 0, stream>>>(w1, w1b, HID, N1);
    gemm8p<1, 1><<<5 * (N1 / 256), 512, 0, stream>>>(xmt, w1b, b1, hqkv, a2t,
                                                     HID / 64, HID / 64, N1 / 256);
    convB_kernel<<<(A2W / 64) * (HID / 64), 256, 0, stream>>>(w2, w2b, A2W, HID);
    qkv_post<<<SEQ, 256, 0, stream>>>(hqkv, fc, fs, qn, kn, qb, kb, vb);
    attn_kernel<<<dim3(SEQ / 64, NHEADS), 256, 0, stream>>>(qb, kb, vb, a2t);
    gemm8p<2, 4><<<4 * 5 * (HID / 256), 512, 0, stream>>>(a2t, w2b, nullptr, part2, nullptr,
                                                          A2W / 64, A2W / 64 / 4, HID / 256);
    ksplit_reduce<<<SEQ * HID / 1024, 256, 0, stream>>>(part2, x, b2, mod + 2 * HID, out);
}